// Round 1
// baseline (499.931 us; speedup 1.0000x reference)
//
#include <hip/hip_runtime.h>
#include <hip/hip_bf16.h>

#define NN 50000
#define EE 800000
#define GG 64
#define CC 8

__device__ __forceinline__ float lrelu(float z) { return fmaxf(z, 0.2f * z); }

__device__ __forceinline__ float wmax(float v) {
#pragma unroll
    for (int o = 32; o; o >>= 1) v = fmaxf(v, __shfl_xor(v, o));
    return v;
}
__device__ __forceinline__ float wsum(float v) {
#pragma unroll
    for (int o = 32; o; o >>= 1) v += __shfl_xor(v, o);
    return v;
}

// ---------------- CSR build ----------------

__global__ void k_init(int* __restrict__ cnt_arr, float* __restrict__ pool, float* __restrict__ cntf) {
    int i = blockIdx.x * 256 + threadIdx.x;
    if (i < NN) cnt_arr[i] = 0;
    if (i < GG * CC) pool[i] = 0.f;
    if (i < GG) cntf[i] = 0.f;
}

__global__ void k_hist(const int* __restrict__ dst, int* __restrict__ cnt) {
    int e = blockIdx.x * 256 + threadIdx.x;
    if (e < EE) atomicAdd(&cnt[dst[e]], 1);
}

// per-block exclusive scan; rowptr[i] = excl-within-block, bsums[b] = block total
__global__ void k_scan1(const int* __restrict__ cnt, int* __restrict__ rowptr, int* __restrict__ bsums) {
    __shared__ int s[256];
    int t = threadIdx.x;
    int i = blockIdx.x * 256 + t;
    int c = (i < NN) ? cnt[i] : 0;
    s[t] = c;
    __syncthreads();
#pragma unroll
    for (int off = 1; off < 256; off <<= 1) {
        int u = (t >= off) ? s[t - off] : 0;
        __syncthreads();
        s[t] += u;
        __syncthreads();
    }
    int incl = s[t];
    if (i < NN) rowptr[i] = incl - c;
    if (t == 255) bsums[blockIdx.x] = incl;
}

__global__ void k_scan2(int* __restrict__ bsums) {
    __shared__ int s[256];
    int t = threadIdx.x;
    int v = (t < 196) ? bsums[t] : 0;
    s[t] = v;
    __syncthreads();
#pragma unroll
    for (int off = 1; off < 256; off <<= 1) {
        int u = (t >= off) ? s[t - off] : 0;
        __syncthreads();
        s[t] += u;
        __syncthreads();
    }
    if (t < 196) bsums[t] = s[t] - v;  // exclusive
}

__global__ void k_scan3(int* __restrict__ rowptr, const int* __restrict__ bsums, int* __restrict__ cursor) {
    int i = blockIdx.x * 256 + threadIdx.x;
    if (i < NN) {
        int r = rowptr[i] + bsums[i >> 8];
        rowptr[i] = r;
        cursor[i] = r;
    }
    if (i == 0) rowptr[NN] = EE;
}

__global__ void k_scatter(const int* __restrict__ src, const int* __restrict__ dst,
                          int* __restrict__ cursor, int* __restrict__ col) {
    int e = blockIdx.x * 256 + threadIdx.x;
    if (e < EE) {
        int d = dst[e];
        int pos = atomicAdd(&cursor[d], 1);
        col[pos] = src[e];
    }
}

// ---------------- dense h = x @ W (out=64), plus alpha scalars ----------------

template <int IN>
__global__ __launch_bounds__(256) void k_mm64(const float* __restrict__ x, const float* __restrict__ W,
                                              const float* __restrict__ avs, const float* __restrict__ avd,
                                              float* __restrict__ h, float* __restrict__ as_,
                                              float* __restrict__ ad_) {
    __shared__ float Wl[IN * 64];
    for (int idx = threadIdx.x; idx < IN * 64; idx += 256) Wl[idx] = W[idx];
    __syncthreads();
    int node = blockIdx.x * 4 + (threadIdx.x >> 6);
    int lane = threadIdx.x & 63;
    if (node >= NN) return;
    const float* xr = x + node * IN;
    float acc = 0.f;
#pragma unroll
    for (int k = 0; k < IN; k++) acc += xr[k] * Wl[k * 64 + lane];
    h[node * 64 + lane] = acc;
    float vs = acc * avs[lane];
    float vd = acc * avd[lane];
#pragma unroll
    for (int o = 32; o; o >>= 1) {
        vs += __shfl_xor(vs, o);
        vd += __shfl_xor(vd, o);
    }
    if (lane == 0) {
        as_[node] = vs;
        ad_[node] = vd;
    }
}

// layer 3: h3 = x @ W3 (64x8) + alpha scalars; wave per node
__global__ __launch_bounds__(256) void k_mm8(const float* __restrict__ x, const float* __restrict__ W,
                                             const float* __restrict__ avs, const float* __restrict__ avd,
                                             float* __restrict__ h3, float* __restrict__ as_,
                                             float* __restrict__ ad_) {
    __shared__ float Wl[512];
    for (int idx = threadIdx.x; idx < 512; idx += 256) Wl[idx] = W[idx];
    __syncthreads();
    int node = blockIdx.x * 4 + (threadIdx.x >> 6);
    int lane = threadIdx.x & 63;
    if (node >= NN) return;
    int f = lane & 7, kc = lane >> 3;
    const float* xr = x + node * 64;
    float acc = 0.f;
#pragma unroll
    for (int j = 0; j < 8; j++) {
        int k = kc * 8 + j;
        acc += xr[k] * Wl[k * 8 + f];
    }
    acc += __shfl_xor(acc, 8);
    acc += __shfl_xor(acc, 16);
    acc += __shfl_xor(acc, 32);  // now every lane has h3[f = lane&7]
    if (lane < 8) h3[node * 8 + lane] = acc;
    float vs = 0.f, vd = 0.f;
    if (lane < 8) {
        vs = acc * avs[lane];
        vd = acc * avd[lane];
    }
    vs += __shfl_xor(vs, 1); vs += __shfl_xor(vs, 2); vs += __shfl_xor(vs, 4);
    vd += __shfl_xor(vd, 1); vd += __shfl_xor(vd, 2); vd += __shfl_xor(vd, 4);
    if (lane == 0) {
        as_[node] = vs;
        ad_[node] = vd;
    }
}

// ---------------- GAT aggregation (softmax over incoming edges incl. self loop) ----------------

__global__ __launch_bounds__(256) void k_agg64(const float* __restrict__ h, const int* __restrict__ rowptr,
                                               const int* __restrict__ col, const float* __restrict__ as_,
                                               const float* __restrict__ ad_, const float* __restrict__ bias,
                                               float* __restrict__ out) {
    int node = blockIdx.x * 4 + (threadIdx.x >> 6);
    int lane = threadIdx.x & 63;
    if (node >= NN) return;
    int rp0 = rowptr[node];
    int deg = rowptr[node + 1] - rp0;
    float adn = ad_[node];
    float zself = as_[node] + adn;
    // phase A: max over z (leaky_relu monotone -> max e = lrelu(max z))
    float zm = zself;
    for (int i = lane; i < deg; i += 64) zm = fmaxf(zm, as_[col[rp0 + i]] + adn);
    zm = wmax(zm);
    float Em = lrelu(zm);
    // phase B: denominator
    float dsum = (lane == 0) ? __expf(lrelu(zself) - Em) : 0.f;
    for (int i = lane; i < deg; i += 64) dsum += __expf(lrelu(as_[col[rp0 + i]] + adn) - Em);
    dsum = wsum(dsum);
    float inv = 1.f / dsum;
    // phase C: weighted feature sum; lane = feature
    float acc = __expf(lrelu(zself) - Em) * inv * h[node * 64 + lane];
    for (int i = 0; i < deg; ++i) {
        int s = col[rp0 + i];
        float al = __expf(lrelu(as_[s] + adn) - Em) * inv;
        acc += al * h[s * 64 + lane];
    }
    out[node * 64 + lane] = fmaxf(acc + bias[lane], 0.f);
}

__global__ __launch_bounds__(256) void k_agg8(const float* __restrict__ h, const int* __restrict__ rowptr,
                                              const int* __restrict__ col, const float* __restrict__ as_,
                                              const float* __restrict__ ad_, const float* __restrict__ bias,
                                              float* __restrict__ out) {
    int node = blockIdx.x * 4 + (threadIdx.x >> 6);
    int lane = threadIdx.x & 63;
    if (node >= NN) return;
    int rp0 = rowptr[node];
    int deg = rowptr[node + 1] - rp0;
    float adn = ad_[node];
    float zself = as_[node] + adn;
    float zm = zself;
    for (int i = lane; i < deg; i += 64) zm = fmaxf(zm, as_[col[rp0 + i]] + adn);
    zm = wmax(zm);
    float Em = lrelu(zm);
    float dsum = (lane == 0) ? __expf(lrelu(zself) - Em) : 0.f;
    for (int i = lane; i < deg; i += 64) dsum += __expf(lrelu(as_[col[rp0 + i]] + adn) - Em);
    dsum = wsum(dsum);
    float inv = 1.f / dsum;
    int f = lane & 7, eg = lane >> 3;  // 8 edges in parallel, 8 features each
    float acc = 0.f;
    for (int base = 0; base < deg; base += 8) {
        int i = base + eg;
        if (i < deg) {
            int s = col[rp0 + i];
            float al = __expf(lrelu(as_[s] + adn) - Em) * inv;
            acc += al * h[s * 8 + f];
        }
    }
    if (eg == 0) acc += __expf(lrelu(zself) - Em) * inv * h[node * 8 + f];
    acc += __shfl_xor(acc, 8);
    acc += __shfl_xor(acc, 16);
    acc += __shfl_xor(acc, 32);
    if (lane < 8) out[node * 8 + lane] = fmaxf(acc + bias[lane], 0.f);
}

// ---------------- global mean pool + sigmoid ----------------

__global__ __launch_bounds__(256) void k_pool(const float* __restrict__ h3, const int* __restrict__ batch,
                                              float* __restrict__ pool, float* __restrict__ cntf) {
    __shared__ float pl[GG * CC + GG];
    for (int idx = threadIdx.x; idx < GG * CC + GG; idx += 256) pl[idx] = 0.f;
    __syncthreads();
    int node = blockIdx.x * 256 + threadIdx.x;
    if (node < NN) {
        int g = batch[node];
#pragma unroll
        for (int c = 0; c < CC; c++) atomicAdd(&pl[g * CC + c], h3[node * CC + c]);
        atomicAdd(&pl[GG * CC + g], 1.0f);
    }
    __syncthreads();
    for (int idx = threadIdx.x; idx < GG * CC + GG; idx += 256) {
        float v = pl[idx];
        if (idx < GG * CC)
            atomicAdd(&pool[idx], v);
        else
            atomicAdd(&cntf[idx - GG * CC], v);
    }
}

__global__ void k_final(const float* __restrict__ pool, const float* __restrict__ cntf,
                        float* __restrict__ out) {
    int t = threadIdx.x;
    if (t < GG * CC) {
        int g = t >> 3;
        float c = fmaxf(cntf[g], 1.0f);
        float v = pool[t] / c;
        out[t] = 1.0f / (1.0f + __expf(-v));
    }
}

// ---------------- launch ----------------

extern "C" void kernel_launch(void* const* d_in, const int* in_sizes, int n_in,
                              void* d_out, int out_size, void* d_ws, size_t ws_size,
                              hipStream_t stream) {
    const float* x   = (const float*)d_in[0];
    const int*   ei  = (const int*)d_in[1];   // [2,E]: src = ei, dst = ei+EE
    const int*   bat = (const int*)d_in[3];
    const float* W1  = (const float*)d_in[4];
    const float* a1s = (const float*)d_in[5];
    const float* a1d = (const float*)d_in[6];
    const float* b1  = (const float*)d_in[7];
    const float* W2  = (const float*)d_in[8];
    const float* a2s = (const float*)d_in[9];
    const float* a2d = (const float*)d_in[10];
    const float* b2  = (const float*)d_in[11];
    const float* W3  = (const float*)d_in[12];
    const float* a3s = (const float*)d_in[13];
    const float* a3d = (const float*)d_in[14];
    const float* b3  = (const float*)d_in[15];
    float* out = (float*)d_out;

    // workspace layout (all 4-byte types, ~33 MB)
    float* hA  = (float*)d_ws;          // N*64
    float* hB  = hA + NN * 64;          // N*64
    float* h3a = hB + NN * 64;          // N*8
    float* h3b = h3a + NN * 8;          // N*8
    float* as_ = h3b + NN * 8;          // N
    float* ad_ = as_ + NN;              // N
    int* cnt_arr = (int*)(ad_ + NN);    // N
    int* rowptr  = cnt_arr + NN;        // N+1
    int* cursor  = rowptr + NN + 1;     // N
    int* col     = cursor + NN;         // E
    int* bsums   = col + EE;            // 256
    float* pool  = (float*)(bsums + 256);  // G*C
    float* cntf  = pool + GG * CC;         // G

    const int NB4 = (NN + 3) / 4;        // 12500 (4 nodes/block, wave per node)
    const int NBN = (NN + 255) / 256;    // 196
    const int NBE = (EE + 255) / 256;    // 3125

    // CSR build (per call: ws is re-poisoned)
    k_init<<<NBN, 256, 0, stream>>>(cnt_arr, pool, cntf);
    k_hist<<<NBE, 256, 0, stream>>>(ei + EE, cnt_arr);
    k_scan1<<<NBN, 256, 0, stream>>>(cnt_arr, rowptr, bsums);
    k_scan2<<<1, 256, 0, stream>>>(bsums);
    k_scan3<<<NBN, 256, 0, stream>>>(rowptr, bsums, cursor);
    k_scatter<<<NBE, 256, 0, stream>>>(ei, ei + EE, cursor, col);

    // layer 1: x[N,11] -> hB[N,64]
    k_mm64<11><<<NB4, 256, 0, stream>>>(x, W1, a1s, a1d, hA, as_, ad_);
    k_agg64<<<NB4, 256, 0, stream>>>(hA, rowptr, col, as_, ad_, b1, hB);
    // layer 2: hB -> hB
    k_mm64<64><<<NB4, 256, 0, stream>>>(hB, W2, a2s, a2d, hA, as_, ad_);
    k_agg64<<<NB4, 256, 0, stream>>>(hA, rowptr, col, as_, ad_, b2, hB);
    // layer 3: hB -> h3b[N,8]
    k_mm8<<<NB4, 256, 0, stream>>>(hB, W3, a3s, a3d, h3a, as_, ad_);
    k_agg8<<<NB4, 256, 0, stream>>>(h3a, rowptr, col, as_, ad_, b3, h3b);
    // pool + sigmoid
    k_pool<<<NBN, 256, 0, stream>>>(h3b, bat, pool, cntf);
    k_final<<<1, 512, 0, stream>>>(pool, cntf, out);
}

// Round 2
// 415.921 us; speedup vs baseline: 1.2020x; 1.2020x over previous
//
#include <hip/hip_runtime.h>
#include <hip/hip_bf16.h>

#define NN 50000
#define EE 800000
#define GG 64
#define CC 8

__device__ __forceinline__ float lrelu(float z) { return fmaxf(z, 0.2f * z); }

// ---------------- CSR build ----------------

__global__ void k_init(int* __restrict__ cnt_arr, float* __restrict__ pool, float* __restrict__ cntf) {
    int i = blockIdx.x * 256 + threadIdx.x;
    if (i < NN) cnt_arr[i] = 0;
    if (i < GG * CC) pool[i] = 0.f;
    if (i < GG) cntf[i] = 0.f;
}

__global__ void k_hist(const int* __restrict__ dst, int* __restrict__ cnt) {
    int e = blockIdx.x * 256 + threadIdx.x;
    if (e < EE) atomicAdd(&cnt[dst[e]], 1);
}

__global__ void k_scan1(const int* __restrict__ cnt, int* __restrict__ rowptr, int* __restrict__ bsums) {
    __shared__ int s[256];
    int t = threadIdx.x;
    int i = blockIdx.x * 256 + t;
    int c = (i < NN) ? cnt[i] : 0;
    s[t] = c;
    __syncthreads();
#pragma unroll
    for (int off = 1; off < 256; off <<= 1) {
        int u = (t >= off) ? s[t - off] : 0;
        __syncthreads();
        s[t] += u;
        __syncthreads();
    }
    int incl = s[t];
    if (i < NN) rowptr[i] = incl - c;
    if (t == 255) bsums[blockIdx.x] = incl;
}

__global__ void k_scan2(int* __restrict__ bsums) {
    __shared__ int s[256];
    int t = threadIdx.x;
    int v = (t < 196) ? bsums[t] : 0;
    s[t] = v;
    __syncthreads();
#pragma unroll
    for (int off = 1; off < 256; off <<= 1) {
        int u = (t >= off) ? s[t - off] : 0;
        __syncthreads();
        s[t] += u;
        __syncthreads();
    }
    if (t < 196) bsums[t] = s[t] - v;  // exclusive
}

__global__ void k_scan3(int* __restrict__ rowptr, const int* __restrict__ bsums, int* __restrict__ cursor) {
    int i = blockIdx.x * 256 + threadIdx.x;
    if (i < NN) {
        int r = rowptr[i] + bsums[i >> 8];
        rowptr[i] = r;
        cursor[i] = r;
    }
    if (i == 0) rowptr[NN] = EE;
}

__global__ void k_scatter(const int* __restrict__ src, const int* __restrict__ dst,
                          int* __restrict__ cursor, int* __restrict__ col) {
    int e = blockIdx.x * 256 + threadIdx.x;
    if (e < EE) {
        int d = dst[e];
        int pos = atomicAdd(&cursor[d], 1);
        col[pos] = src[e];
    }
}

// ---------------- dense h = x @ W (out=64), plus alpha scalars ----------------
// wave per node; x row read ONCE coalesced (xr[lane]) then broadcast via shuffle.

template <int IN>
__global__ __launch_bounds__(256) void k_mm64(const float* __restrict__ x, const float* __restrict__ W,
                                              const float* __restrict__ avs, const float* __restrict__ avd,
                                              float* __restrict__ h, float* __restrict__ as_,
                                              float* __restrict__ ad_) {
    __shared__ float Wl[IN * 64];
    for (int idx = threadIdx.x; idx < IN * 64; idx += 256) Wl[idx] = W[idx];
    __syncthreads();
    int node = blockIdx.x * 4 + (threadIdx.x >> 6);
    int lane = threadIdx.x & 63;
    if (node >= NN) return;
    float xv = (lane < IN) ? x[node * IN + lane] : 0.f;
    float acc = 0.f;
#pragma unroll
    for (int k = 0; k < IN; k++) acc += __shfl(xv, k) * Wl[k * 64 + lane];
    h[node * 64 + lane] = acc;
    float vs = acc * avs[lane];
    float vd = acc * avd[lane];
#pragma unroll
    for (int o = 32; o; o >>= 1) {
        vs += __shfl_xor(vs, o);
        vd += __shfl_xor(vd, o);
    }
    if (lane == 0) {
        as_[node] = vs;
        ad_[node] = vd;
    }
}

// layer 3: h3 = x @ W3 (64x8) + alpha scalars; wave per node
__global__ __launch_bounds__(256) void k_mm8(const float* __restrict__ x, const float* __restrict__ W,
                                             const float* __restrict__ avs, const float* __restrict__ avd,
                                             float* __restrict__ h3, float* __restrict__ as_,
                                             float* __restrict__ ad_) {
    __shared__ float Wl[512];
    for (int idx = threadIdx.x; idx < 512; idx += 256) Wl[idx] = W[idx];
    __syncthreads();
    int node = blockIdx.x * 4 + (threadIdx.x >> 6);
    int lane = threadIdx.x & 63;
    if (node >= NN) return;
    int f = lane & 7, kc = lane >> 3;
    float xv = x[node * 64 + lane];  // coalesced
    float acc = 0.f;
#pragma unroll
    for (int j = 0; j < 8; j++) {
        int k = kc * 8 + j;
        acc += __shfl(xv, k) * Wl[k * 8 + f];
    }
    acc += __shfl_xor(acc, 8);
    acc += __shfl_xor(acc, 16);
    acc += __shfl_xor(acc, 32);  // every lane: h3[f = lane&7]
    if (lane < 8) h3[node * 8 + lane] = acc;
    float vs = 0.f, vd = 0.f;
    if (lane < 8) {
        vs = acc * avs[lane];
        vd = acc * avd[lane];
    }
    vs += __shfl_xor(vs, 1); vs += __shfl_xor(vs, 2); vs += __shfl_xor(vs, 4);
    vd += __shfl_xor(vd, 1); vd += __shfl_xor(vd, 2); vd += __shfl_xor(vd, 4);
    if (lane == 0) {
        as_[node] = vs;
        ad_[node] = vd;
    }
}

// ---------------- GAT aggregation ----------------
// Online-softmax single pass (max+denom), then 4-edge x float4 feature pass.

__global__ __launch_bounds__(256) void k_agg64(const float* __restrict__ h, const int* __restrict__ rowptr,
                                               const int* __restrict__ col, const float* __restrict__ as_,
                                               const float* __restrict__ ad_, const float* __restrict__ bias,
                                               float* __restrict__ out) {
    int node = blockIdx.x * 4 + (threadIdx.x >> 6);
    int lane = threadIdx.x & 63;
    if (node >= NN) return;
    int rp0 = rowptr[node];
    int deg = rowptr[node + 1] - rp0;
    float adn = ad_[node];
    float zself = lrelu(as_[node] + adn);
    // phase A+B fused: per-lane online softmax state, then wave merge
    float m = -1e30f, l = 0.f;
    for (int i = lane; i < deg; i += 64) {
        float z = lrelu(as_[col[rp0 + i]] + adn);
        float mn = fmaxf(m, z);
        l = l * __expf(m - mn) + __expf(z - mn);
        m = mn;
    }
    if (lane == 0) {  // self loop
        float mn = fmaxf(m, zself);
        l = l * __expf(m - mn) + __expf(zself - mn);
        m = mn;
    }
#pragma unroll
    for (int o = 32; o; o >>= 1) {
        float mo = __shfl_xor(m, o), lo = __shfl_xor(l, o);
        float mn = fmaxf(m, mo);
        l = l * __expf(m - mn) + lo * __expf(mo - mn);
        m = mn;
    }
    float Em = m;
    float inv = 1.f / l;
    // phase C: 4 edges in parallel, float4 per lane, 2x manual unroll (8 rows in flight)
    int f = lane & 15, eg = lane >> 4;
    const float4* h4 = (const float4*)h;
    float4 acc = make_float4(0.f, 0.f, 0.f, 0.f);
    int base = 0;
    for (; base + 8 <= deg; base += 8) {
        int sa = col[rp0 + base + eg];
        int sb = col[rp0 + base + 4 + eg];
        float za = as_[sa], zb = as_[sb];
        float4 ha = h4[sa * 16 + f];
        float4 hb = h4[sb * 16 + f];
        float ala = __expf(lrelu(za + adn) - Em) * inv;
        float alb = __expf(lrelu(zb + adn) - Em) * inv;
        acc.x += ala * ha.x + alb * hb.x;
        acc.y += ala * ha.y + alb * hb.y;
        acc.z += ala * ha.z + alb * hb.z;
        acc.w += ala * ha.w + alb * hb.w;
    }
    for (; base < deg; base += 4) {
        int i = base + eg;
        if (i < deg) {
            int s = col[rp0 + i];
            float al = __expf(lrelu(as_[s] + adn) - Em) * inv;
            float4 hv = h4[s * 16 + f];
            acc.x += al * hv.x;
            acc.y += al * hv.y;
            acc.z += al * hv.z;
            acc.w += al * hv.w;
        }
    }
    if (eg == 0) {  // self loop
        float al = __expf(zself - Em) * inv;
        float4 hv = h4[node * 16 + f];
        acc.x += al * hv.x;
        acc.y += al * hv.y;
        acc.z += al * hv.z;
        acc.w += al * hv.w;
    }
#pragma unroll
    for (int o = 16; o <= 32; o <<= 1) {
        acc.x += __shfl_xor(acc.x, o);
        acc.y += __shfl_xor(acc.y, o);
        acc.z += __shfl_xor(acc.z, o);
        acc.w += __shfl_xor(acc.w, o);
    }
    if (eg == 0) {
        float4 bv = ((const float4*)bias)[f];
        float4 o4;
        o4.x = fmaxf(acc.x + bv.x, 0.f);
        o4.y = fmaxf(acc.y + bv.y, 0.f);
        o4.z = fmaxf(acc.z + bv.z, 0.f);
        o4.w = fmaxf(acc.w + bv.w, 0.f);
        ((float4*)out)[node * 16 + f] = o4;
    }
}

// layer-3 aggregation: rows of 8 floats; 16 edges in parallel, float2 per lane
__global__ __launch_bounds__(256) void k_agg8(const float* __restrict__ h, const int* __restrict__ rowptr,
                                              const int* __restrict__ col, const float* __restrict__ as_,
                                              const float* __restrict__ ad_, const float* __restrict__ bias,
                                              float* __restrict__ out) {
    int node = blockIdx.x * 4 + (threadIdx.x >> 6);
    int lane = threadIdx.x & 63;
    if (node >= NN) return;
    int rp0 = rowptr[node];
    int deg = rowptr[node + 1] - rp0;
    float adn = ad_[node];
    float zself = lrelu(as_[node] + adn);
    float m = -1e30f, l = 0.f;
    for (int i = lane; i < deg; i += 64) {
        float z = lrelu(as_[col[rp0 + i]] + adn);
        float mn = fmaxf(m, z);
        l = l * __expf(m - mn) + __expf(z - mn);
        m = mn;
    }
    if (lane == 0) {
        float mn = fmaxf(m, zself);
        l = l * __expf(m - mn) + __expf(zself - mn);
        m = mn;
    }
#pragma unroll
    for (int o = 32; o; o >>= 1) {
        float mo = __shfl_xor(m, o), lo = __shfl_xor(l, o);
        float mn = fmaxf(m, mo);
        l = l * __expf(m - mn) + lo * __expf(mo - mn);
        m = mn;
    }
    float Em = m;
    float inv = 1.f / l;
    int f = lane & 3, eg = lane >> 2;  // 16 edges x float2
    const float2* h2v = (const float2*)h;
    float2 acc = make_float2(0.f, 0.f);
    for (int base = 0; base < deg; base += 16) {
        int i = base + eg;
        if (i < deg) {
            int s = col[rp0 + i];
            float al = __expf(lrelu(as_[s] + adn) - Em) * inv;
            float2 hv = h2v[s * 4 + f];
            acc.x += al * hv.x;
            acc.y += al * hv.y;
        }
    }
    if (eg == 0) {
        float al = __expf(zself - Em) * inv;
        float2 hv = h2v[node * 4 + f];
        acc.x += al * hv.x;
        acc.y += al * hv.y;
    }
#pragma unroll
    for (int o = 4; o <= 32; o <<= 1) {
        acc.x += __shfl_xor(acc.x, o);
        acc.y += __shfl_xor(acc.y, o);
    }
    if (eg == 0) {
        float2 bv = ((const float2*)bias)[f];
        float2 o2;
        o2.x = fmaxf(acc.x + bv.x, 0.f);
        o2.y = fmaxf(acc.y + bv.y, 0.f);
        ((float2*)out)[node * 4 + f] = o2;
    }
}

// ---------------- global mean pool + sigmoid ----------------

__global__ __launch_bounds__(256) void k_pool(const float* __restrict__ h3, const int* __restrict__ batch,
                                              float* __restrict__ pool, float* __restrict__ cntf) {
    __shared__ float pl[GG * CC + GG];
    for (int idx = threadIdx.x; idx < GG * CC + GG; idx += 256) pl[idx] = 0.f;
    __syncthreads();
    int node = blockIdx.x * 256 + threadIdx.x;
    if (node < NN) {
        int g = batch[node];
#pragma unroll
        for (int c = 0; c < CC; c++) atomicAdd(&pl[g * CC + c], h3[node * CC + c]);
        atomicAdd(&pl[GG * CC + g], 1.0f);
    }
    __syncthreads();
    for (int idx = threadIdx.x; idx < GG * CC + GG; idx += 256) {
        float v = pl[idx];
        if (idx < GG * CC)
            atomicAdd(&pool[idx], v);
        else
            atomicAdd(&cntf[idx - GG * CC], v);
    }
}

__global__ void k_final(const float* __restrict__ pool, const float* __restrict__ cntf,
                        float* __restrict__ out) {
    int t = threadIdx.x;
    if (t < GG * CC) {
        int g = t >> 3;
        float c = fmaxf(cntf[g], 1.0f);
        float v = pool[t] / c;
        out[t] = 1.0f / (1.0f + __expf(-v));
    }
}

// ---------------- launch ----------------

extern "C" void kernel_launch(void* const* d_in, const int* in_sizes, int n_in,
                              void* d_out, int out_size, void* d_ws, size_t ws_size,
                              hipStream_t stream) {
    const float* x   = (const float*)d_in[0];
    const int*   ei  = (const int*)d_in[1];   // [2,E]: src = ei, dst = ei+EE
    const int*   bat = (const int*)d_in[3];
    const float* W1  = (const float*)d_in[4];
    const float* a1s = (const float*)d_in[5];
    const float* a1d = (const float*)d_in[6];
    const float* b1  = (const float*)d_in[7];
    const float* W2  = (const float*)d_in[8];
    const float* a2s = (const float*)d_in[9];
    const float* a2d = (const float*)d_in[10];
    const float* b2  = (const float*)d_in[11];
    const float* W3  = (const float*)d_in[12];
    const float* a3s = (const float*)d_in[13];
    const float* a3d = (const float*)d_in[14];
    const float* b3  = (const float*)d_in[15];
    float* out = (float*)d_out;

    float* hA  = (float*)d_ws;          // N*64
    float* hB  = hA + NN * 64;          // N*64
    float* h3a = hB + NN * 64;          // N*8
    float* h3b = h3a + NN * 8;          // N*8
    float* as_ = h3b + NN * 8;          // N
    float* ad_ = as_ + NN;              // N
    int* cnt_arr = (int*)(ad_ + NN);    // N
    int* rowptr  = cnt_arr + NN;        // N+1
    int* cursor  = rowptr + NN + 1;     // N
    int* col     = cursor + NN;         // E
    int* bsums   = col + EE;            // 256
    float* pool  = (float*)(bsums + 256);  // G*C
    float* cntf  = pool + GG * CC;         // G

    const int NB4 = (NN + 3) / 4;
    const int NBN = (NN + 255) / 256;
    const int NBE = (EE + 255) / 256;

    k_init<<<NBN, 256, 0, stream>>>(cnt_arr, pool, cntf);
    k_hist<<<NBE, 256, 0, stream>>>(ei + EE, cnt_arr);
    k_scan1<<<NBN, 256, 0, stream>>>(cnt_arr, rowptr, bsums);
    k_scan2<<<1, 256, 0, stream>>>(bsums);
    k_scan3<<<NBN, 256, 0, stream>>>(rowptr, bsums, cursor);
    k_scatter<<<NBE, 256, 0, stream>>>(ei, ei + EE, cursor, col);

    k_mm64<11><<<NB4, 256, 0, stream>>>(x, W1, a1s, a1d, hA, as_, ad_);
    k_agg64<<<NB4, 256, 0, stream>>>(hA, rowptr, col, as_, ad_, b1, hB);
    k_mm64<64><<<NB4, 256, 0, stream>>>(hB, W2, a2s, a2d, hA, as_, ad_);
    k_agg64<<<NB4, 256, 0, stream>>>(hA, rowptr, col, as_, ad_, b2, hB);
    k_mm8<<<NB4, 256, 0, stream>>>(hB, W3, a3s, a3d, h3a, as_, ad_);
    k_agg8<<<NB4, 256, 0, stream>>>(h3a, rowptr, col, as_, ad_, b3, h3b);
    k_pool<<<NBN, 256, 0, stream>>>(h3b, bat, pool, cntf);
    k_final<<<1, 512, 0, stream>>>(pool, cntf, out);
}

// Round 3
// 365.000 us; speedup vs baseline: 1.3697x; 1.1395x over previous
//
#include <hip/hip_runtime.h>
#include <hip/hip_bf16.h>

#define NN 50000
#define EE 800000
#define GG 64
#define CC 8

__device__ __forceinline__ float lrelu(float z) { return fmaxf(z, 0.2f * z); }

// ---------------- CSR build ----------------

__global__ void k_init(int* __restrict__ cnt_arr, float* __restrict__ pool, float* __restrict__ cntf) {
    int i = blockIdx.x * 256 + threadIdx.x;
    if (i < NN) cnt_arr[i] = 0;
    if (i < GG * CC) pool[i] = 0.f;
    if (i < GG) cntf[i] = 0.f;
}

__global__ void k_hist(const int* __restrict__ dst, int* __restrict__ cnt) {
    int e = blockIdx.x * 256 + threadIdx.x;
    if (e < EE) atomicAdd(&cnt[dst[e]], 1);
}

__global__ void k_scan1(const int* __restrict__ cnt, int* __restrict__ rowptr, int* __restrict__ bsums) {
    __shared__ int s[256];
    int t = threadIdx.x;
    int i = blockIdx.x * 256 + t;
    int c = (i < NN) ? cnt[i] : 0;
    s[t] = c;
    __syncthreads();
#pragma unroll
    for (int off = 1; off < 256; off <<= 1) {
        int u = (t >= off) ? s[t - off] : 0;
        __syncthreads();
        s[t] += u;
        __syncthreads();
    }
    int incl = s[t];
    if (i < NN) rowptr[i] = incl - c;
    if (t == 255) bsums[blockIdx.x] = incl;
}

__global__ void k_scan2(int* __restrict__ bsums) {
    __shared__ int s[256];
    int t = threadIdx.x;
    int v = (t < 196) ? bsums[t] : 0;
    s[t] = v;
    __syncthreads();
#pragma unroll
    for (int off = 1; off < 256; off <<= 1) {
        int u = (t >= off) ? s[t - off] : 0;
        __syncthreads();
        s[t] += u;
        __syncthreads();
    }
    if (t < 196) bsums[t] = s[t] - v;  // exclusive
}

__global__ void k_scan3(int* __restrict__ rowptr, const int* __restrict__ bsums, int* __restrict__ cursor) {
    int i = blockIdx.x * 256 + threadIdx.x;
    if (i < NN) {
        int r = rowptr[i] + bsums[i >> 8];
        rowptr[i] = r;
        cursor[i] = r;
    }
    if (i == 0) rowptr[NN] = EE;
}

__global__ void k_scatter(const int* __restrict__ src, const int* __restrict__ dst,
                          int* __restrict__ cursor, int* __restrict__ col) {
    int e = blockIdx.x * 256 + threadIdx.x;
    if (e < EE) {
        int d = dst[e];
        int pos = atomicAdd(&cursor[d], 1);
        col[pos] = src[e];
    }
}

// ---------------- tiled h = x @ W (out=64) + alpha scalars ----------------
// 64-node tile per block; thread computes 4 nodes x 4 features.
// xT pad 68: float4-aligned, conflict-free reads (4 distinct addrs/wave, distinct banks).

template <int IN>
__global__ __launch_bounds__(256) void k_mm64t(const float* __restrict__ x, const float* __restrict__ W,
                                               const float* __restrict__ avs, const float* __restrict__ avd,
                                               float* __restrict__ h, float* __restrict__ as_,
                                               float* __restrict__ ad_) {
    __shared__ float xT[IN * 68];   // xT[k*68 + n]
    __shared__ float Wl[IN * 64];   // Wl[k*64 + f]
    __shared__ float avl[64], adl[64];
    int t = threadIdx.x;
    int nbase = blockIdx.x * 64;
    for (int idx = t; idx < IN * 64; idx += 256) Wl[idx] = W[idx];
    if (t < 64) { avl[t] = avs[t]; adl[t] = avd[t]; }
    for (int idx = t; idx < 64 * IN; idx += 256) {
        int n = idx / IN, k = idx - n * IN;
        int gn = nbase + n;
        if (gn >= NN) gn = NN - 1;
        xT[k * 68 + n] = x[gn * IN + k];
    }
    __syncthreads();
    int f0 = (t & 15) * 4;   // feature group
    int n0 = (t >> 4) * 4;   // node group (within wave: quarter q -> nodes q*4..q*4+3 of its 16)
    float a00=0,a01=0,a02=0,a03=0, a10=0,a11=0,a12=0,a13=0;
    float a20=0,a21=0,a22=0,a23=0, a30=0,a31=0,a32=0,a33=0;
#pragma unroll 4
    for (int k = 0; k < IN; k++) {
        float4 xv = *(const float4*)&xT[k * 68 + n0];
        float4 wv = *(const float4*)&Wl[k * 64 + f0];
        a00 += xv.x * wv.x; a01 += xv.x * wv.y; a02 += xv.x * wv.z; a03 += xv.x * wv.w;
        a10 += xv.y * wv.x; a11 += xv.y * wv.y; a12 += xv.y * wv.z; a13 += xv.y * wv.w;
        a20 += xv.z * wv.x; a21 += xv.z * wv.y; a22 += xv.z * wv.z; a23 += xv.z * wv.w;
        a30 += xv.w * wv.x; a31 += xv.w * wv.y; a32 += xv.w * wv.z; a33 += xv.w * wv.w;
    }
    float4 av = *(const float4*)&avl[f0];
    float4 dv = *(const float4*)&adl[f0];
    // per-node partial attention dots + store h rows (float4, coalesced per quarter-wave)
    float vs[4], vd[4];
    vs[0] = a00*av.x + a01*av.y + a02*av.z + a03*av.w;
    vs[1] = a10*av.x + a11*av.y + a12*av.z + a13*av.w;
    vs[2] = a20*av.x + a21*av.y + a22*av.z + a23*av.w;
    vs[3] = a30*av.x + a31*av.y + a32*av.z + a33*av.w;
    vd[0] = a00*dv.x + a01*dv.y + a02*dv.z + a03*dv.w;
    vd[1] = a10*dv.x + a11*dv.y + a12*dv.z + a13*dv.w;
    vd[2] = a20*dv.x + a21*dv.y + a22*dv.z + a23*dv.w;
    vd[3] = a30*dv.x + a31*dv.y + a32*dv.z + a33*dv.w;
#pragma unroll
    for (int o = 1; o < 16; o <<= 1) {
#pragma unroll
        for (int ni = 0; ni < 4; ni++) {
            vs[ni] += __shfl_xor(vs[ni], o);
            vd[ni] += __shfl_xor(vd[ni], o);
        }
    }
    float4* h4 = (float4*)h;
    int nn0 = nbase + n0;
    if (nn0 + 3 < NN) {
        h4[(nn0 + 0) * 16 + (t & 15)] = make_float4(a00, a01, a02, a03);
        h4[(nn0 + 1) * 16 + (t & 15)] = make_float4(a10, a11, a12, a13);
        h4[(nn0 + 2) * 16 + (t & 15)] = make_float4(a20, a21, a22, a23);
        h4[(nn0 + 3) * 16 + (t & 15)] = make_float4(a30, a31, a32, a33);
        if ((t & 15) == 0) {
#pragma unroll
            for (int ni = 0; ni < 4; ni++) { as_[nn0 + ni] = vs[ni]; ad_[nn0 + ni] = vd[ni]; }
        }
    } else {
        float rows[4][4] = {{a00,a01,a02,a03},{a10,a11,a12,a13},{a20,a21,a22,a23},{a30,a31,a32,a33}};
#pragma unroll
        for (int ni = 0; ni < 4; ni++) {
            if (nn0 + ni < NN) {
                h4[(nn0 + ni) * 16 + (t & 15)] = make_float4(rows[ni][0], rows[ni][1], rows[ni][2], rows[ni][3]);
                if ((t & 15) == 0) { as_[nn0 + ni] = vs[ni]; ad_[nn0 + ni] = vd[ni]; }
            }
        }
    }
}

// layer 3: h3 = x @ W3 (64x8) + alpha scalars; wave per node
__global__ __launch_bounds__(256) void k_mm8(const float* __restrict__ x, const float* __restrict__ W,
                                             const float* __restrict__ avs, const float* __restrict__ avd,
                                             float* __restrict__ h3, float* __restrict__ as_,
                                             float* __restrict__ ad_) {
    __shared__ float Wl[512];
    for (int idx = threadIdx.x; idx < 512; idx += 256) Wl[idx] = W[idx];
    __syncthreads();
    int node = blockIdx.x * 4 + (threadIdx.x >> 6);
    int lane = threadIdx.x & 63;
    if (node >= NN) return;
    int f = lane & 7, kc = lane >> 3;
    float xv = x[node * 64 + lane];  // coalesced
    float acc = 0.f;
#pragma unroll
    for (int j = 0; j < 8; j++) {
        int k = kc * 8 + j;
        acc += __shfl(xv, k) * Wl[k * 8 + f];
    }
    acc += __shfl_xor(acc, 8);
    acc += __shfl_xor(acc, 16);
    acc += __shfl_xor(acc, 32);  // every lane: h3[f = lane&7]
    if (lane < 8) h3[node * 8 + lane] = acc;
    float vs = 0.f, vd = 0.f;
    if (lane < 8) {
        vs = acc * avs[lane];
        vd = acc * avd[lane];
    }
    vs += __shfl_xor(vs, 1); vs += __shfl_xor(vs, 2); vs += __shfl_xor(vs, 4);
    vd += __shfl_xor(vd, 1); vd += __shfl_xor(vd, 2); vd += __shfl_xor(vd, 4);
    if (lane == 0) {
        as_[node] = vs;
        ad_[node] = vd;
    }
}

// ---------------- GAT aggregation ----------------

__global__ __launch_bounds__(256) void k_agg64(const float* __restrict__ h, const int* __restrict__ rowptr,
                                               const int* __restrict__ col, const float* __restrict__ as_,
                                               const float* __restrict__ ad_, const float* __restrict__ bias,
                                               float* __restrict__ out) {
    int node = blockIdx.x * 4 + (threadIdx.x >> 6);
    int lane = threadIdx.x & 63;
    if (node >= NN) return;
    int rp0 = rowptr[node];
    int deg = rowptr[node + 1] - rp0;
    float adn = ad_[node];
    float zself = lrelu(as_[node] + adn);
    float m = -1e30f, l = 0.f;
    for (int i = lane; i < deg; i += 64) {
        float z = lrelu(as_[col[rp0 + i]] + adn);
        float mn = fmaxf(m, z);
        l = l * __expf(m - mn) + __expf(z - mn);
        m = mn;
    }
    if (lane == 0) {
        float mn = fmaxf(m, zself);
        l = l * __expf(m - mn) + __expf(zself - mn);
        m = mn;
    }
#pragma unroll
    for (int o = 32; o; o >>= 1) {
        float mo = __shfl_xor(m, o), lo = __shfl_xor(l, o);
        float mn = fmaxf(m, mo);
        l = l * __expf(m - mn) + lo * __expf(mo - mn);
        m = mn;
    }
    float Em = m;
    float inv = 1.f / l;
    int f = lane & 15, eg = lane >> 4;
    const float4* h4 = (const float4*)h;
    float4 acc = make_float4(0.f, 0.f, 0.f, 0.f);
    int base = 0;
    for (; base + 8 <= deg; base += 8) {
        int sa = col[rp0 + base + eg];
        int sb = col[rp0 + base + 4 + eg];
        float za = as_[sa], zb = as_[sb];
        float4 ha = h4[sa * 16 + f];
        float4 hb = h4[sb * 16 + f];
        float ala = __expf(lrelu(za + adn) - Em) * inv;
        float alb = __expf(lrelu(zb + adn) - Em) * inv;
        acc.x += ala * ha.x + alb * hb.x;
        acc.y += ala * ha.y + alb * hb.y;
        acc.z += ala * ha.z + alb * hb.z;
        acc.w += ala * ha.w + alb * hb.w;
    }
    for (; base < deg; base += 4) {
        int i = base + eg;
        if (i < deg) {
            int s = col[rp0 + i];
            float al = __expf(lrelu(as_[s] + adn) - Em) * inv;
            float4 hv = h4[s * 16 + f];
            acc.x += al * hv.x;
            acc.y += al * hv.y;
            acc.z += al * hv.z;
            acc.w += al * hv.w;
        }
    }
    if (eg == 0) {
        float al = __expf(zself - Em) * inv;
        float4 hv = h4[node * 16 + f];
        acc.x += al * hv.x;
        acc.y += al * hv.y;
        acc.z += al * hv.z;
        acc.w += al * hv.w;
    }
#pragma unroll
    for (int o = 16; o <= 32; o <<= 1) {
        acc.x += __shfl_xor(acc.x, o);
        acc.y += __shfl_xor(acc.y, o);
        acc.z += __shfl_xor(acc.z, o);
        acc.w += __shfl_xor(acc.w, o);
    }
    if (eg == 0) {
        float4 bv = ((const float4*)bias)[f];
        float4 o4;
        o4.x = fmaxf(acc.x + bv.x, 0.f);
        o4.y = fmaxf(acc.y + bv.y, 0.f);
        o4.z = fmaxf(acc.z + bv.z, 0.f);
        o4.w = fmaxf(acc.w + bv.w, 0.f);
        ((float4*)out)[node * 16 + f] = o4;
    }
}

__global__ __launch_bounds__(256) void k_agg8(const float* __restrict__ h, const int* __restrict__ rowptr,
                                              const int* __restrict__ col, const float* __restrict__ as_,
                                              const float* __restrict__ ad_, const float* __restrict__ bias,
                                              float* __restrict__ out) {
    int node = blockIdx.x * 4 + (threadIdx.x >> 6);
    int lane = threadIdx.x & 63;
    if (node >= NN) return;
    int rp0 = rowptr[node];
    int deg = rowptr[node + 1] - rp0;
    float adn = ad_[node];
    float zself = lrelu(as_[node] + adn);
    float m = -1e30f, l = 0.f;
    for (int i = lane; i < deg; i += 64) {
        float z = lrelu(as_[col[rp0 + i]] + adn);
        float mn = fmaxf(m, z);
        l = l * __expf(m - mn) + __expf(z - mn);
        m = mn;
    }
    if (lane == 0) {
        float mn = fmaxf(m, zself);
        l = l * __expf(m - mn) + __expf(zself - mn);
        m = mn;
    }
#pragma unroll
    for (int o = 32; o; o >>= 1) {
        float mo = __shfl_xor(m, o), lo = __shfl_xor(l, o);
        float mn = fmaxf(m, mo);
        l = l * __expf(m - mn) + lo * __expf(mo - mn);
        m = mn;
    }
    float Em = m;
    float inv = 1.f / l;
    int f = lane & 3, eg = lane >> 2;  // 16 edges x float2
    const float2* h2v = (const float2*)h;
    float2 acc = make_float2(0.f, 0.f);
    for (int base = 0; base < deg; base += 16) {
        int i = base + eg;
        if (i < deg) {
            int s = col[rp0 + i];
            float al = __expf(lrelu(as_[s] + adn) - Em) * inv;
            float2 hv = h2v[s * 4 + f];
            acc.x += al * hv.x;
            acc.y += al * hv.y;
        }
    }
    if (eg == 0) {
        float al = __expf(zself - Em) * inv;
        float2 hv = h2v[node * 4 + f];
        acc.x += al * hv.x;
        acc.y += al * hv.y;
    }
#pragma unroll
    for (int o = 4; o <= 32; o <<= 1) {
        acc.x += __shfl_xor(acc.x, o);
        acc.y += __shfl_xor(acc.y, o);
    }
    if (eg == 0) {
        float2 bv = ((const float2*)bias)[f];
        float2 o2;
        o2.x = fmaxf(acc.x + bv.x, 0.f);
        o2.y = fmaxf(acc.y + bv.y, 0.f);
        ((float2*)out)[node * 4 + f] = o2;
    }
}

// ---------------- global mean pool + sigmoid ----------------

__global__ __launch_bounds__(256) void k_pool(const float* __restrict__ h3, const int* __restrict__ batch,
                                              float* __restrict__ pool, float* __restrict__ cntf) {
    __shared__ float pl[GG * CC + GG];
    for (int idx = threadIdx.x; idx < GG * CC + GG; idx += 256) pl[idx] = 0.f;
    __syncthreads();
    int node = blockIdx.x * 256 + threadIdx.x;
    if (node < NN) {
        int g = batch[node];
#pragma unroll
        for (int c = 0; c < CC; c++) atomicAdd(&pl[g * CC + c], h3[node * CC + c]);
        atomicAdd(&pl[GG * CC + g], 1.0f);
    }
    __syncthreads();
    for (int idx = threadIdx.x; idx < GG * CC + GG; idx += 256) {
        float v = pl[idx];
        if (idx < GG * CC)
            atomicAdd(&pool[idx], v);
        else
            atomicAdd(&cntf[idx - GG * CC], v);
    }
}

__global__ void k_final(const float* __restrict__ pool, const float* __restrict__ cntf,
                        float* __restrict__ out) {
    int t = threadIdx.x;
    if (t < GG * CC) {
        int g = t >> 3;
        float c = fmaxf(cntf[g], 1.0f);
        float v = pool[t] / c;
        out[t] = 1.0f / (1.0f + __expf(-v));
    }
}

// ---------------- launch ----------------

extern "C" void kernel_launch(void* const* d_in, const int* in_sizes, int n_in,
                              void* d_out, int out_size, void* d_ws, size_t ws_size,
                              hipStream_t stream) {
    const float* x   = (const float*)d_in[0];
    const int*   ei  = (const int*)d_in[1];
    const int*   bat = (const int*)d_in[3];
    const float* W1  = (const float*)d_in[4];
    const float* a1s = (const float*)d_in[5];
    const float* a1d = (const float*)d_in[6];
    const float* b1  = (const float*)d_in[7];
    const float* W2  = (const float*)d_in[8];
    const float* a2s = (const float*)d_in[9];
    const float* a2d = (const float*)d_in[10];
    const float* b2  = (const float*)d_in[11];
    const float* W3  = (const float*)d_in[12];
    const float* a3s = (const float*)d_in[13];
    const float* a3d = (const float*)d_in[14];
    const float* b3  = (const float*)d_in[15];
    float* out = (float*)d_out;

    float* hA  = (float*)d_ws;          // N*64
    float* hB  = hA + NN * 64;          // N*64
    float* h3a = hB + NN * 64;          // N*8
    float* h3b = h3a + NN * 8;          // N*8
    float* as_ = h3b + NN * 8;          // N
    float* ad_ = as_ + NN;              // N
    int* cnt_arr = (int*)(ad_ + NN);    // N
    int* rowptr  = cnt_arr + NN;        // N+1
    int* cursor  = rowptr + NN + 1;     // N
    int* col     = cursor + NN;         // E
    int* bsums   = col + EE;            // 256
    float* pool  = (float*)(bsums + 256);  // G*C
    float* cntf  = pool + GG * CC;         // G

    const int NB4  = (NN + 3) / 4;
    const int NB64 = (NN + 63) / 64;     // 782 tiles
    const int NBN  = (NN + 255) / 256;
    const int NBE  = (EE + 255) / 256;

    k_init<<<NBN, 256, 0, stream>>>(cnt_arr, pool, cntf);
    k_hist<<<NBE, 256, 0, stream>>>(ei + EE, cnt_arr);
    k_scan1<<<NBN, 256, 0, stream>>>(cnt_arr, rowptr, bsums);
    k_scan2<<<1, 256, 0, stream>>>(bsums);
    k_scan3<<<NBN, 256, 0, stream>>>(rowptr, bsums, cursor);
    k_scatter<<<NBE, 256, 0, stream>>>(ei, ei + EE, cursor, col);

    k_mm64t<11><<<NB64, 256, 0, stream>>>(x, W1, a1s, a1d, hA, as_, ad_);
    k_agg64<<<NB4, 256, 0, stream>>>(hA, rowptr, col, as_, ad_, b1, hB);
    k_mm64t<64><<<NB64, 256, 0, stream>>>(hB, W2, a2s, a2d, hA, as_, ad_);
    k_agg64<<<NB4, 256, 0, stream>>>(hA, rowptr, col, as_, ad_, b2, hB);
    k_mm8<<<NB4, 256, 0, stream>>>(hB, W3, a3s, a3d, h3a, as_, ad_);
    k_agg8<<<NB4, 256, 0, stream>>>(h3a, rowptr, col, as_, ad_, b3, h3b);
    k_pool<<<NBN, 256, 0, stream>>>(h3b, bat, pool, cntf);
    k_final<<<1, 512, 0, stream>>>(pool, cntf, out);
}

// Round 4
// 313.416 us; speedup vs baseline: 1.5951x; 1.1646x over previous
//
#include <hip/hip_runtime.h>
#include <hip/hip_bf16.h>

#define NN 50000
#define EE 800000
#define GG 64
#define CC 8

#define NBKT 196      // ceil(50000/256) buckets of 256 nodes
#define CHUNK 4096
#define NCHK 196      // ceil(800000/4096)
#define CAP 8192      // max edges per bucket (mean 4082, sd 64 -> 8192 is ~64 sigma)

__device__ __forceinline__ float lrelu(float z) { return fmaxf(z, 0.2f * z); }

// ---------------- CSR build: two-level counting sort (no global atomics) ----------------

__global__ __launch_bounds__(256) void kA1(const int* __restrict__ dst, int* __restrict__ G) {
    __shared__ int hist[NBKT];
    int t = threadIdx.x;
    for (int i = t; i < NBKT; i += 256) hist[i] = 0;
    __syncthreads();
    int e0 = blockIdx.x * CHUNK;
    int e1 = min(e0 + CHUNK, EE);
    for (int e = e0 + t; e < e1; e += 256) atomicAdd(&hist[dst[e] >> 8], 1);
    __syncthreads();
    for (int i = t; i < NBKT; i += 256) G[blockIdx.x * NBKT + i] = hist[i];
}

// per-bucket exclusive scan across chunks; bT[j] = bucket total
__global__ __launch_bounds__(256) void kA2(const int* __restrict__ G, int* __restrict__ offs,
                                           int* __restrict__ bT) {
    __shared__ int s[256];
    int t = threadIdx.x, j = blockIdx.x;
    int v = (t < NCHK) ? G[t * NBKT + j] : 0;
    s[t] = v;
    __syncthreads();
#pragma unroll
    for (int off = 1; off < 256; off <<= 1) {
        int u = (t >= off) ? s[t - off] : 0;
        __syncthreads();
        s[t] += u;
        __syncthreads();
    }
    if (t < NCHK) offs[t * NBKT + j] = s[t] - v;
    if (t == 255) bT[j] = s[255];
}

// bucket bases + misc zero-init
__global__ __launch_bounds__(256) void kA2b(const int* __restrict__ bT, int* __restrict__ bstart,
                                            float* __restrict__ pool, float* __restrict__ cntf,
                                            int* __restrict__ rowptr) {
    __shared__ int s[256];
    int t = threadIdx.x;
    int v = (t < NBKT) ? bT[t] : 0;
    s[t] = v;
    __syncthreads();
#pragma unroll
    for (int off = 1; off < 256; off <<= 1) {
        int u = (t >= off) ? s[t - off] : 0;
        __syncthreads();
        s[t] += u;
        __syncthreads();
    }
    if (t < NBKT) bstart[t] = s[t] - v;
    if (t == 0) { bstart[NBKT] = EE; rowptr[NN] = EE; }
    for (int i = t; i < GG * CC; i += 256) pool[i] = 0.f;
    if (t < GG) cntf[t] = 0.f;
}

// partition edges into bucket-ordered (src,dst) pairs
__global__ __launch_bounds__(256) void kA3(const int* __restrict__ src, const int* __restrict__ dst,
                                           const int* __restrict__ offs, const int* __restrict__ bstart,
                                           uint2* __restrict__ pairs) {
    __shared__ int cur[NBKT];
    int t = threadIdx.x, c = blockIdx.x;
    for (int i = t; i < NBKT; i += 256) cur[i] = bstart[i] + offs[c * NBKT + i];
    __syncthreads();
    int e0 = c * CHUNK, e1 = min(e0 + CHUNK, EE);
    for (int e = e0 + t; e < e1; e += 256) {
        int d = dst[e];
        int pos = atomicAdd(&cur[d >> 8], 1);
        pairs[pos] = make_uint2((unsigned)src[e], (unsigned)d);
    }
}

// per-bucket local counting sort -> col + rowptr
__global__ __launch_bounds__(256) void kB(const uint2* __restrict__ pairs, const int* __restrict__ bstart,
                                          int* __restrict__ col, int* __restrict__ rowptr) {
    __shared__ int srcL[CAP];
    __shared__ unsigned short dstL[CAP];
    __shared__ int hist[256];
    __shared__ int sc[256];
    int t = threadIdx.x, j = blockIdx.x;
    int start = bstart[j], end = bstart[j + 1];
    int cnt = end - start;
    if (cnt > CAP) cnt = CAP;  // never triggers (defensive)
    int nb = j * 256;
    int nodeCnt = min(256, NN - nb);
    hist[t] = 0;
    __syncthreads();
    for (int i = t; i < cnt; i += 256) {
        uint2 p = pairs[start + i];
        srcL[i] = (int)p.x;
        int dl = (int)p.y - nb;
        dstL[i] = (unsigned short)dl;
        atomicAdd(&hist[dl], 1);
    }
    __syncthreads();
    int c = hist[t];
    sc[t] = c;
    __syncthreads();
#pragma unroll
    for (int off = 1; off < 256; off <<= 1) {
        int u = (t >= off) ? sc[t - off] : 0;
        __syncthreads();
        sc[t] += u;
        __syncthreads();
    }
    int excl = sc[t] - c;
    if (t < nodeCnt) rowptr[nb + t] = start + excl;
    hist[t] = excl;  // reuse as cursor
    __syncthreads();
    for (int i = t; i < cnt; i += 256) {
        int dl = dstL[i];
        int pos = atomicAdd(&hist[dl], 1);
        col[start + pos] = srcL[i];
    }
}

// ---------------- tiled h = x @ W (out=64) + alpha scalars ----------------

template <int IN>
__global__ __launch_bounds__(256) void k_mm64t(const float* __restrict__ x, const float* __restrict__ W,
                                               const float* __restrict__ avs, const float* __restrict__ avd,
                                               float* __restrict__ h, float* __restrict__ as_,
                                               float* __restrict__ ad_) {
    __shared__ float xT[IN * 68];
    __shared__ float Wl[IN * 64];
    __shared__ float avl[64], adl[64];
    int t = threadIdx.x;
    int nbase = blockIdx.x * 64;
    for (int idx = t; idx < IN * 64; idx += 256) Wl[idx] = W[idx];
    if (t < 64) { avl[t] = avs[t]; adl[t] = avd[t]; }
    for (int idx = t; idx < 64 * IN; idx += 256) {
        int n = idx / IN, k = idx - n * IN;
        int gn = nbase + n;
        if (gn >= NN) gn = NN - 1;
        xT[k * 68 + n] = x[gn * IN + k];
    }
    __syncthreads();
    int f0 = (t & 15) * 4;
    int n0 = (t >> 4) * 4;
    float a00=0,a01=0,a02=0,a03=0, a10=0,a11=0,a12=0,a13=0;
    float a20=0,a21=0,a22=0,a23=0, a30=0,a31=0,a32=0,a33=0;
#pragma unroll 4
    for (int k = 0; k < IN; k++) {
        float4 xv = *(const float4*)&xT[k * 68 + n0];
        float4 wv = *(const float4*)&Wl[k * 64 + f0];
        a00 += xv.x * wv.x; a01 += xv.x * wv.y; a02 += xv.x * wv.z; a03 += xv.x * wv.w;
        a10 += xv.y * wv.x; a11 += xv.y * wv.y; a12 += xv.y * wv.z; a13 += xv.y * wv.w;
        a20 += xv.z * wv.x; a21 += xv.z * wv.y; a22 += xv.z * wv.z; a23 += xv.z * wv.w;
        a30 += xv.w * wv.x; a31 += xv.w * wv.y; a32 += xv.w * wv.z; a33 += xv.w * wv.w;
    }
    float4 av = *(const float4*)&avl[f0];
    float4 dv = *(const float4*)&adl[f0];
    float vs[4], vd[4];
    vs[0] = a00*av.x + a01*av.y + a02*av.z + a03*av.w;
    vs[1] = a10*av.x + a11*av.y + a12*av.z + a13*av.w;
    vs[2] = a20*av.x + a21*av.y + a22*av.z + a23*av.w;
    vs[3] = a30*av.x + a31*av.y + a32*av.z + a33*av.w;
    vd[0] = a00*dv.x + a01*dv.y + a02*dv.z + a03*dv.w;
    vd[1] = a10*dv.x + a11*dv.y + a12*dv.z + a13*dv.w;
    vd[2] = a20*dv.x + a21*dv.y + a22*dv.z + a23*dv.w;
    vd[3] = a30*dv.x + a31*dv.y + a32*dv.z + a33*dv.w;
#pragma unroll
    for (int o = 1; o < 16; o <<= 1) {
#pragma unroll
        for (int ni = 0; ni < 4; ni++) {
            vs[ni] += __shfl_xor(vs[ni], o);
            vd[ni] += __shfl_xor(vd[ni], o);
        }
    }
    float4* h4 = (float4*)h;
    int nn0 = nbase + n0;
    if (nn0 + 3 < NN) {
        h4[(nn0 + 0) * 16 + (t & 15)] = make_float4(a00, a01, a02, a03);
        h4[(nn0 + 1) * 16 + (t & 15)] = make_float4(a10, a11, a12, a13);
        h4[(nn0 + 2) * 16 + (t & 15)] = make_float4(a20, a21, a22, a23);
        h4[(nn0 + 3) * 16 + (t & 15)] = make_float4(a30, a31, a32, a33);
        if ((t & 15) == 0) {
#pragma unroll
            for (int ni = 0; ni < 4; ni++) { as_[nn0 + ni] = vs[ni]; ad_[nn0 + ni] = vd[ni]; }
        }
    } else {
        float rows[4][4] = {{a00,a01,a02,a03},{a10,a11,a12,a13},{a20,a21,a22,a23},{a30,a31,a32,a33}};
#pragma unroll
        for (int ni = 0; ni < 4; ni++) {
            if (nn0 + ni < NN) {
                h4[(nn0 + ni) * 16 + (t & 15)] = make_float4(rows[ni][0], rows[ni][1], rows[ni][2], rows[ni][3]);
                if ((t & 15) == 0) { as_[nn0 + ni] = vs[ni]; ad_[nn0 + ni] = vd[ni]; }
            }
        }
    }
}

__global__ __launch_bounds__(256) void k_mm8(const float* __restrict__ x, const float* __restrict__ W,
                                             const float* __restrict__ avs, const float* __restrict__ avd,
                                             float* __restrict__ h3, float* __restrict__ as_,
                                             float* __restrict__ ad_) {
    __shared__ float Wl[512];
    for (int idx = threadIdx.x; idx < 512; idx += 256) Wl[idx] = W[idx];
    __syncthreads();
    int node = blockIdx.x * 4 + (threadIdx.x >> 6);
    int lane = threadIdx.x & 63;
    if (node >= NN) return;
    int f = lane & 7, kc = lane >> 3;
    float xv = x[node * 64 + lane];
    float acc = 0.f;
#pragma unroll
    for (int j = 0; j < 8; j++) {
        int k = kc * 8 + j;
        acc += __shfl(xv, k) * Wl[k * 8 + f];
    }
    acc += __shfl_xor(acc, 8);
    acc += __shfl_xor(acc, 16);
    acc += __shfl_xor(acc, 32);
    if (lane < 8) h3[node * 8 + lane] = acc;
    float vs = 0.f, vd = 0.f;
    if (lane < 8) {
        vs = acc * avs[lane];
        vd = acc * avd[lane];
    }
    vs += __shfl_xor(vs, 1); vs += __shfl_xor(vs, 2); vs += __shfl_xor(vs, 4);
    vd += __shfl_xor(vd, 1); vd += __shfl_xor(vd, 2); vd += __shfl_xor(vd, 4);
    if (lane == 0) {
        as_[node] = vs;
        ad_[node] = vd;
    }
}

// ---------------- GAT aggregation ----------------

__global__ __launch_bounds__(256) void k_agg64(const float* __restrict__ h, const int* __restrict__ rowptr,
                                               const int* __restrict__ col, const float* __restrict__ as_,
                                               const float* __restrict__ ad_, const float* __restrict__ bias,
                                               float* __restrict__ out) {
    int node = blockIdx.x * 4 + (threadIdx.x >> 6);
    int lane = threadIdx.x & 63;
    if (node >= NN) return;
    int rp0 = rowptr[node];
    int deg = rowptr[node + 1] - rp0;
    float adn = ad_[node];
    float zself = lrelu(as_[node] + adn);
    float m = -1e30f, l = 0.f;
    for (int i = lane; i < deg; i += 64) {
        float z = lrelu(as_[col[rp0 + i]] + adn);
        float mn = fmaxf(m, z);
        l = l * __expf(m - mn) + __expf(z - mn);
        m = mn;
    }
    if (lane == 0) {
        float mn = fmaxf(m, zself);
        l = l * __expf(m - mn) + __expf(zself - mn);
        m = mn;
    }
#pragma unroll
    for (int o = 32; o; o >>= 1) {
        float mo = __shfl_xor(m, o), lo = __shfl_xor(l, o);
        float mn = fmaxf(m, mo);
        l = l * __expf(m - mn) + lo * __expf(mo - mn);
        m = mn;
    }
    float Em = m;
    float inv = 1.f / l;
    int f = lane & 15, eg = lane >> 4;
    const float4* h4 = (const float4*)h;
    float4 acc = make_float4(0.f, 0.f, 0.f, 0.f);
    int base = 0;
    for (; base + 8 <= deg; base += 8) {
        int sa = col[rp0 + base + eg];
        int sb = col[rp0 + base + 4 + eg];
        float za = as_[sa], zb = as_[sb];
        float4 ha = h4[sa * 16 + f];
        float4 hb = h4[sb * 16 + f];
        float ala = __expf(lrelu(za + adn) - Em) * inv;
        float alb = __expf(lrelu(zb + adn) - Em) * inv;
        acc.x += ala * ha.x + alb * hb.x;
        acc.y += ala * ha.y + alb * hb.y;
        acc.z += ala * ha.z + alb * hb.z;
        acc.w += ala * ha.w + alb * hb.w;
    }
    for (; base < deg; base += 4) {
        int i = base + eg;
        if (i < deg) {
            int s = col[rp0 + i];
            float al = __expf(lrelu(as_[s] + adn) - Em) * inv;
            float4 hv = h4[s * 16 + f];
            acc.x += al * hv.x;
            acc.y += al * hv.y;
            acc.z += al * hv.z;
            acc.w += al * hv.w;
        }
    }
    if (eg == 0) {
        float al = __expf(zself - Em) * inv;
        float4 hv = h4[node * 16 + f];
        acc.x += al * hv.x;
        acc.y += al * hv.y;
        acc.z += al * hv.z;
        acc.w += al * hv.w;
    }
#pragma unroll
    for (int o = 16; o <= 32; o <<= 1) {
        acc.x += __shfl_xor(acc.x, o);
        acc.y += __shfl_xor(acc.y, o);
        acc.z += __shfl_xor(acc.z, o);
        acc.w += __shfl_xor(acc.w, o);
    }
    if (eg == 0) {
        float4 bv = ((const float4*)bias)[f];
        float4 o4;
        o4.x = fmaxf(acc.x + bv.x, 0.f);
        o4.y = fmaxf(acc.y + bv.y, 0.f);
        o4.z = fmaxf(acc.z + bv.z, 0.f);
        o4.w = fmaxf(acc.w + bv.w, 0.f);
        ((float4*)out)[node * 16 + f] = o4;
    }
}

__global__ __launch_bounds__(256) void k_agg8(const float* __restrict__ h, const int* __restrict__ rowptr,
                                              const int* __restrict__ col, const float* __restrict__ as_,
                                              const float* __restrict__ ad_, const float* __restrict__ bias,
                                              float* __restrict__ out) {
    int node = blockIdx.x * 4 + (threadIdx.x >> 6);
    int lane = threadIdx.x & 63;
    if (node >= NN) return;
    int rp0 = rowptr[node];
    int deg = rowptr[node + 1] - rp0;
    float adn = ad_[node];
    float zself = lrelu(as_[node] + adn);
    float m = -1e30f, l = 0.f;
    for (int i = lane; i < deg; i += 64) {
        float z = lrelu(as_[col[rp0 + i]] + adn);
        float mn = fmaxf(m, z);
        l = l * __expf(m - mn) + __expf(z - mn);
        m = mn;
    }
    if (lane == 0) {
        float mn = fmaxf(m, zself);
        l = l * __expf(m - mn) + __expf(zself - mn);
        m = mn;
    }
#pragma unroll
    for (int o = 32; o; o >>= 1) {
        float mo = __shfl_xor(m, o), lo = __shfl_xor(l, o);
        float mn = fmaxf(m, mo);
        l = l * __expf(m - mn) + lo * __expf(mo - mn);
        m = mn;
    }
    float Em = m;
    float inv = 1.f / l;
    int f = lane & 3, eg = lane >> 2;
    const float2* h2v = (const float2*)h;
    float2 acc = make_float2(0.f, 0.f);
    for (int base = 0; base < deg; base += 16) {
        int i = base + eg;
        if (i < deg) {
            int s = col[rp0 + i];
            float al = __expf(lrelu(as_[s] + adn) - Em) * inv;
            float2 hv = h2v[s * 4 + f];
            acc.x += al * hv.x;
            acc.y += al * hv.y;
        }
    }
    if (eg == 0) {
        float al = __expf(zself - Em) * inv;
        float2 hv = h2v[node * 4 + f];
        acc.x += al * hv.x;
        acc.y += al * hv.y;
    }
#pragma unroll
    for (int o = 4; o <= 32; o <<= 1) {
        acc.x += __shfl_xor(acc.x, o);
        acc.y += __shfl_xor(acc.y, o);
    }
    if (eg == 0) {
        float2 bv = ((const float2*)bias)[f];
        float2 o2;
        o2.x = fmaxf(acc.x + bv.x, 0.f);
        o2.y = fmaxf(acc.y + bv.y, 0.f);
        ((float2*)out)[node * 4 + f] = o2;
    }
}

// ---------------- global mean pool + sigmoid ----------------

__global__ __launch_bounds__(256) void k_pool(const float* __restrict__ h3, const int* __restrict__ batch,
                                              float* __restrict__ pool, float* __restrict__ cntf) {
    __shared__ float pl[GG * CC + GG];
    for (int idx = threadIdx.x; idx < GG * CC + GG; idx += 256) pl[idx] = 0.f;
    __syncthreads();
    int node = blockIdx.x * 256 + threadIdx.x;
    if (node < NN) {
        int g = batch[node];
#pragma unroll
        for (int c = 0; c < CC; c++) atomicAdd(&pl[g * CC + c], h3[node * CC + c]);
        atomicAdd(&pl[GG * CC + g], 1.0f);
    }
    __syncthreads();
    for (int idx = threadIdx.x; idx < GG * CC + GG; idx += 256) {
        float v = pl[idx];
        if (idx < GG * CC)
            atomicAdd(&pool[idx], v);
        else
            atomicAdd(&cntf[idx - GG * CC], v);
    }
}

__global__ void k_final(const float* __restrict__ pool, const float* __restrict__ cntf,
                        float* __restrict__ out) {
    int t = threadIdx.x;
    if (t < GG * CC) {
        int g = t >> 3;
        float c = fmaxf(cntf[g], 1.0f);
        float v = pool[t] / c;
        out[t] = 1.0f / (1.0f + __expf(-v));
    }
}

// ---------------- launch ----------------

extern "C" void kernel_launch(void* const* d_in, const int* in_sizes, int n_in,
                              void* d_out, int out_size, void* d_ws, size_t ws_size,
                              hipStream_t stream) {
    const float* x   = (const float*)d_in[0];
    const int*   ei  = (const int*)d_in[1];
    const int*   bat = (const int*)d_in[3];
    const float* W1  = (const float*)d_in[4];
    const float* a1s = (const float*)d_in[5];
    const float* a1d = (const float*)d_in[6];
    const float* b1  = (const float*)d_in[7];
    const float* W2  = (const float*)d_in[8];
    const float* a2s = (const float*)d_in[9];
    const float* a2d = (const float*)d_in[10];
    const float* b2  = (const float*)d_in[11];
    const float* W3  = (const float*)d_in[12];
    const float* a3s = (const float*)d_in[13];
    const float* a3d = (const float*)d_in[14];
    const float* b3  = (const float*)d_in[15];
    float* out = (float*)d_out;

    float* hA  = (float*)d_ws;          // N*64 ; pairs aliases here (used only pre-mm)
    float* hB  = hA + NN * 64;          // N*64
    float* h3a = hB + NN * 64;          // N*8
    float* h3b = h3a + NN * 8;          // N*8
    float* as_ = h3b + NN * 8;          // N
    float* ad_ = as_ + NN;              // N
    int* rowptr  = (int*)(ad_ + NN);    // N+1
    int* col     = rowptr + NN + 1;     // E
    int* G       = col + EE;            // NCHK*NBKT
    int* offs    = G + NCHK * NBKT;     // NCHK*NBKT
    int* bT      = offs + NCHK * NBKT;  // NBKT
    int* bstart  = bT + NBKT;           // NBKT+1
    float* pool  = (float*)(bstart + NBKT + 1);  // G*C
    float* cntf  = pool + GG * CC;               // G
    uint2* pairs = (uint2*)hA;          // E pairs (6.4MB <= 12.8MB), dead before mm64t writes hA

    const int NB4  = (NN + 3) / 4;
    const int NB64 = (NN + 63) / 64;
    const int NBN  = (NN + 255) / 256;

    const int* srcE = ei;
    const int* dstE = ei + EE;

    // CSR build via two-level counting sort (no global atomics)
    kA1<<<NCHK, 256, 0, stream>>>(dstE, G);
    kA2<<<NBKT, 256, 0, stream>>>(G, offs, bT);
    kA2b<<<1, 256, 0, stream>>>(bT, bstart, pool, cntf, rowptr);
    kA3<<<NCHK, 256, 0, stream>>>(srcE, dstE, offs, bstart, pairs);
    kB<<<NBKT, 256, 0, stream>>>(pairs, bstart, col, rowptr);

    k_mm64t<11><<<NB64, 256, 0, stream>>>(x, W1, a1s, a1d, hA, as_, ad_);
    k_agg64<<<NB4, 256, 0, stream>>>(hA, rowptr, col, as_, ad_, b1, hB);
    k_mm64t<64><<<NB64, 256, 0, stream>>>(hB, W2, a2s, a2d, hA, as_, ad_);
    k_agg64<<<NB4, 256, 0, stream>>>(hA, rowptr, col, as_, ad_, b2, hB);
    k_mm8<<<NB4, 256, 0, stream>>>(hB, W3, a3s, a3d, h3a, as_, ad_);
    k_agg8<<<NB4, 256, 0, stream>>>(h3a, rowptr, col, as_, ad_, b3, h3b);
    k_pool<<<NBN, 256, 0, stream>>>(h3b, bat, pool, cntf);
    k_final<<<1, 512, 0, stream>>>(pool, cntf, out);
}

// Round 5
// 307.177 us; speedup vs baseline: 1.6275x; 1.0203x over previous
//
#include <hip/hip_runtime.h>
#include <hip/hip_bf16.h>

#define NN 50000
#define EE 800000
#define GG 64
#define CC 8

#define NBKT 196      // ceil(50000/256) buckets of 256 nodes
#define CHUNK 4096
#define NCHK 196      // ceil(800000/4096)
#define CAP 8192      // max edges per bucket (mean 4082)

__device__ __forceinline__ float lrelu(float z) { return fmaxf(z, 0.2f * z); }

// ---------------- CSR build: two-level counting sort (no global atomics) ----------------

__global__ __launch_bounds__(256) void kA1(const int* __restrict__ dst, int* __restrict__ G) {
    __shared__ int hist[NBKT];
    int t = threadIdx.x;
    for (int i = t; i < NBKT; i += 256) hist[i] = 0;
    __syncthreads();
    int e0 = blockIdx.x * CHUNK;
    int e1 = min(e0 + CHUNK, EE);
    for (int e = e0 + t; e < e1; e += 256) atomicAdd(&hist[dst[e] >> 8], 1);
    __syncthreads();
    for (int i = t; i < NBKT; i += 256) G[blockIdx.x * NBKT + i] = hist[i];
}

__global__ __launch_bounds__(256) void kA2(const int* __restrict__ G, int* __restrict__ offs,
                                           int* __restrict__ bT) {
    __shared__ int s[256];
    int t = threadIdx.x, j = blockIdx.x;
    int v = (t < NCHK) ? G[t * NBKT + j] : 0;
    s[t] = v;
    __syncthreads();
#pragma unroll
    for (int off = 1; off < 256; off <<= 1) {
        int u = (t >= off) ? s[t - off] : 0;
        __syncthreads();
        s[t] += u;
        __syncthreads();
    }
    if (t < NCHK) offs[t * NBKT + j] = s[t] - v;
    if (t == 255) bT[j] = s[255];
}

__global__ __launch_bounds__(256) void kA2b(const int* __restrict__ bT, int* __restrict__ bstart,
                                            float* __restrict__ pool, float* __restrict__ cntf,
                                            int* __restrict__ rowptr) {
    __shared__ int s[256];
    int t = threadIdx.x;
    int v = (t < NBKT) ? bT[t] : 0;
    s[t] = v;
    __syncthreads();
#pragma unroll
    for (int off = 1; off < 256; off <<= 1) {
        int u = (t >= off) ? s[t - off] : 0;
        __syncthreads();
        s[t] += u;
        __syncthreads();
    }
    if (t < NBKT) bstart[t] = s[t] - v;
    if (t == 0) { bstart[NBKT] = EE; rowptr[NN] = EE; }
    for (int i = t; i < GG * CC; i += 256) pool[i] = 0.f;
    if (t < GG) cntf[t] = 0.f;
}

__global__ __launch_bounds__(256) void kA3(const int* __restrict__ src, const int* __restrict__ dst,
                                           const int* __restrict__ offs, const int* __restrict__ bstart,
                                           uint2* __restrict__ pairs) {
    __shared__ int cur[NBKT];
    int t = threadIdx.x, c = blockIdx.x;
    for (int i = t; i < NBKT; i += 256) cur[i] = bstart[i] + offs[c * NBKT + i];
    __syncthreads();
    int e0 = c * CHUNK, e1 = min(e0 + CHUNK, EE);
    for (int e = e0 + t; e < e1; e += 256) {
        int d = dst[e];
        int pos = atomicAdd(&cur[d >> 8], 1);
        pairs[pos] = make_uint2((unsigned)src[e], (unsigned)d);
    }
}

__global__ __launch_bounds__(256) void kB(const uint2* __restrict__ pairs, const int* __restrict__ bstart,
                                          int* __restrict__ col, int* __restrict__ rowptr) {
    __shared__ int srcL[CAP];
    __shared__ unsigned short dstL[CAP];
    __shared__ int hist[256];
    __shared__ int sc[256];
    int t = threadIdx.x, j = blockIdx.x;
    int start = bstart[j], end = bstart[j + 1];
    int cnt = end - start;
    if (cnt > CAP) cnt = CAP;
    int nb = j * 256;
    int nodeCnt = min(256, NN - nb);
    hist[t] = 0;
    __syncthreads();
    for (int i = t; i < cnt; i += 256) {
        uint2 p = pairs[start + i];
        srcL[i] = (int)p.x;
        int dl = (int)p.y - nb;
        dstL[i] = (unsigned short)dl;
        atomicAdd(&hist[dl], 1);
    }
    __syncthreads();
    int c = hist[t];
    sc[t] = c;
    __syncthreads();
#pragma unroll
    for (int off = 1; off < 256; off <<= 1) {
        int u = (t >= off) ? sc[t - off] : 0;
        __syncthreads();
        sc[t] += u;
        __syncthreads();
    }
    int excl = sc[t] - c;
    if (t < nodeCnt) rowptr[nb + t] = start + excl;
    hist[t] = excl;
    __syncthreads();
    for (int i = t; i < cnt; i += 256) {
        int dl = dstL[i];
        int pos = atomicAdd(&hist[dl], 1);
        col[start + pos] = srcL[i];
    }
}

// ---------------- tiled h = x @ W (out=64) + alpha scalars ----------------

template <int IN>
__global__ __launch_bounds__(256) void k_mm64t(const float* __restrict__ x, const float* __restrict__ W,
                                               const float* __restrict__ avs, const float* __restrict__ avd,
                                               float* __restrict__ h, float* __restrict__ as_,
                                               float* __restrict__ ad_) {
    __shared__ float xT[IN * 68];
    __shared__ float Wl[IN * 64];
    __shared__ float avl[64], adl[64];
    int t = threadIdx.x;
    int nbase = blockIdx.x * 64;
    for (int idx = t; idx < IN * 64; idx += 256) Wl[idx] = W[idx];
    if (t < 64) { avl[t] = avs[t]; adl[t] = avd[t]; }
    for (int idx = t; idx < 64 * IN; idx += 256) {
        int n = idx / IN, k = idx - n * IN;
        int gn = nbase + n;
        if (gn >= NN) gn = NN - 1;
        xT[k * 68 + n] = x[gn * IN + k];
    }
    __syncthreads();
    int f0 = (t & 15) * 4;
    int n0 = (t >> 4) * 4;
    float a00=0,a01=0,a02=0,a03=0, a10=0,a11=0,a12=0,a13=0;
    float a20=0,a21=0,a22=0,a23=0, a30=0,a31=0,a32=0,a33=0;
#pragma unroll 4
    for (int k = 0; k < IN; k++) {
        float4 xv = *(const float4*)&xT[k * 68 + n0];
        float4 wv = *(const float4*)&Wl[k * 64 + f0];
        a00 += xv.x * wv.x; a01 += xv.x * wv.y; a02 += xv.x * wv.z; a03 += xv.x * wv.w;
        a10 += xv.y * wv.x; a11 += xv.y * wv.y; a12 += xv.y * wv.z; a13 += xv.y * wv.w;
        a20 += xv.z * wv.x; a21 += xv.z * wv.y; a22 += xv.z * wv.z; a23 += xv.z * wv.w;
        a30 += xv.w * wv.x; a31 += xv.w * wv.y; a32 += xv.w * wv.z; a33 += xv.w * wv.w;
    }
    float4 av = *(const float4*)&avl[f0];
    float4 dv = *(const float4*)&adl[f0];
    float vs[4], vd[4];
    vs[0] = a00*av.x + a01*av.y + a02*av.z + a03*av.w;
    vs[1] = a10*av.x + a11*av.y + a12*av.z + a13*av.w;
    vs[2] = a20*av.x + a21*av.y + a22*av.z + a23*av.w;
    vs[3] = a30*av.x + a31*av.y + a32*av.z + a33*av.w;
    vd[0] = a00*dv.x + a01*dv.y + a02*dv.z + a03*dv.w;
    vd[1] = a10*dv.x + a11*dv.y + a12*dv.z + a13*dv.w;
    vd[2] = a20*dv.x + a21*dv.y + a22*dv.z + a23*dv.w;
    vd[3] = a30*dv.x + a31*dv.y + a32*dv.z + a33*dv.w;
#pragma unroll
    for (int o = 1; o < 16; o <<= 1) {
#pragma unroll
        for (int ni = 0; ni < 4; ni++) {
            vs[ni] += __shfl_xor(vs[ni], o);
            vd[ni] += __shfl_xor(vd[ni], o);
        }
    }
    float4* h4 = (float4*)h;
    int nn0 = nbase + n0;
    if (nn0 + 3 < NN) {
        h4[(nn0 + 0) * 16 + (t & 15)] = make_float4(a00, a01, a02, a03);
        h4[(nn0 + 1) * 16 + (t & 15)] = make_float4(a10, a11, a12, a13);
        h4[(nn0 + 2) * 16 + (t & 15)] = make_float4(a20, a21, a22, a23);
        h4[(nn0 + 3) * 16 + (t & 15)] = make_float4(a30, a31, a32, a33);
        if ((t & 15) == 0) {
#pragma unroll
            for (int ni = 0; ni < 4; ni++) { as_[nn0 + ni] = vs[ni]; ad_[nn0 + ni] = vd[ni]; }
        }
    } else {
        float rows[4][4] = {{a00,a01,a02,a03},{a10,a11,a12,a13},{a20,a21,a22,a23},{a30,a31,a32,a33}};
#pragma unroll
        for (int ni = 0; ni < 4; ni++) {
            if (nn0 + ni < NN) {
                h4[(nn0 + ni) * 16 + (t & 15)] = make_float4(rows[ni][0], rows[ni][1], rows[ni][2], rows[ni][3]);
                if ((t & 15) == 0) { as_[nn0 + ni] = vs[ni]; ad_[nn0 + ni] = vd[ni]; }
            }
        }
    }
}

__global__ __launch_bounds__(256) void k_mm8(const float* __restrict__ x, const float* __restrict__ W,
                                             const float* __restrict__ avs, const float* __restrict__ avd,
                                             float* __restrict__ h3, float* __restrict__ as_,
                                             float* __restrict__ ad_) {
    __shared__ float Wl[512];
    for (int idx = threadIdx.x; idx < 512; idx += 256) Wl[idx] = W[idx];
    __syncthreads();
    int node = blockIdx.x * 4 + (threadIdx.x >> 6);
    int lane = threadIdx.x & 63;
    if (node >= NN) return;
    int f = lane & 7, kc = lane >> 3;
    float xv = x[node * 64 + lane];
    float acc = 0.f;
#pragma unroll
    for (int j = 0; j < 8; j++) {
        int k = kc * 8 + j;
        acc += __shfl(xv, k) * Wl[k * 8 + f];
    }
    acc += __shfl_xor(acc, 8);
    acc += __shfl_xor(acc, 16);
    acc += __shfl_xor(acc, 32);
    if (lane < 8) h3[node * 8 + lane] = acc;
    float vs = 0.f, vd = 0.f;
    if (lane < 8) {
        vs = acc * avs[lane];
        vd = acc * avd[lane];
    }
    vs += __shfl_xor(vs, 1); vs += __shfl_xor(vs, 2); vs += __shfl_xor(vs, 4);
    vd += __shfl_xor(vd, 1); vd += __shfl_xor(vd, 2); vd += __shfl_xor(vd, 4);
    if (lane == 0) {
        as_[node] = vs;
        ad_[node] = vd;
    }
}

// ---------------- GAT aggregation ----------------
// Fast path (deg<=64): lane i owns edge i; weight+src stay in registers,
// phase C fetches them by shuffle — 1 exp/edge, no redundant exp, no col reload.

__global__ __launch_bounds__(256) void k_agg64(const float* __restrict__ h, const int* __restrict__ rowptr,
                                               const int* __restrict__ col, const float* __restrict__ as_,
                                               const float* __restrict__ ad_, const float* __restrict__ bias,
                                               float* __restrict__ out) {
    int node = blockIdx.x * 4 + (threadIdx.x >> 6);
    int lane = threadIdx.x & 63;
    if (node >= NN) return;
    int rp0 = rowptr[node];
    int deg = rowptr[node + 1] - rp0;
    float adn = ad_[node];
    float zself = lrelu(as_[node] + adn);
    const float4* h4 = (const float4*)h;
    int f = lane & 15, eg = lane >> 4;
    float4 acc = make_float4(0.f, 0.f, 0.f, 0.f);
    if (deg <= 64) {
        int s = 0;
        float z = -1e30f;
        if (lane < deg) {
            s = col[rp0 + lane];
            z = lrelu(as_[s] + adn);
        }
        float M = z;
#pragma unroll
        for (int o = 32; o; o >>= 1) M = fmaxf(M, __shfl_xor(M, o));
        M = fmaxf(M, zself);
        float ex = (lane < deg) ? __expf(z - M) : 0.f;
        float exs = __expf(zself - M);
        float sum = ex;
#pragma unroll
        for (int o = 32; o; o >>= 1) sum += __shfl_xor(sum, o);
        float inv = 1.f / (sum + exs);
        float wl = ex * inv;
        int base = 0;
        for (; base + 8 <= deg; base += 8) {
            int ia = base + eg, ib = base + 4 + eg;
            int sa = __shfl(s, ia), sb = __shfl(s, ib);
            float wa = __shfl(wl, ia), wb = __shfl(wl, ib);
            float4 ha = h4[sa * 16 + f];
            float4 hb = h4[sb * 16 + f];
            acc.x += wa * ha.x + wb * hb.x;
            acc.y += wa * ha.y + wb * hb.y;
            acc.z += wa * ha.z + wb * hb.z;
            acc.w += wa * ha.w + wb * hb.w;
        }
        for (; base < deg; base += 4) {
            int ia = base + eg;                 // <= 63 always (deg<=64)
            int sa = __shfl(s, ia);
            float wa = __shfl(wl, ia);          // 0 for ia >= deg
            float4 ha = h4[sa * 16 + f];
            acc.x += wa * ha.x;
            acc.y += wa * ha.y;
            acc.z += wa * ha.z;
            acc.w += wa * ha.w;
        }
        if (eg == 0) {
            float w0 = exs * inv;
            float4 hv = h4[node * 16 + f];
            acc.x += w0 * hv.x;
            acc.y += w0 * hv.y;
            acc.z += w0 * hv.z;
            acc.w += w0 * hv.w;
        }
    } else {
        // generic fallback (rare): online softmax + per-edge recompute
        float m = -1e30f, l = 0.f;
        for (int i = lane; i < deg; i += 64) {
            float z = lrelu(as_[col[rp0 + i]] + adn);
            float mn = fmaxf(m, z);
            l = l * __expf(m - mn) + __expf(z - mn);
            m = mn;
        }
        if (lane == 0) {
            float mn = fmaxf(m, zself);
            l = l * __expf(m - mn) + __expf(zself - mn);
            m = mn;
        }
#pragma unroll
        for (int o = 32; o; o >>= 1) {
            float mo = __shfl_xor(m, o), lo = __shfl_xor(l, o);
            float mn = fmaxf(m, mo);
            l = l * __expf(m - mn) + lo * __expf(mo - mn);
            m = mn;
        }
        float Em = m;
        float inv = 1.f / l;
        for (int base = 0; base < deg; base += 4) {
            int i = base + eg;
            if (i < deg) {
                int sv = col[rp0 + i];
                float al = __expf(lrelu(as_[sv] + adn) - Em) * inv;
                float4 hv = h4[sv * 16 + f];
                acc.x += al * hv.x;
                acc.y += al * hv.y;
                acc.z += al * hv.z;
                acc.w += al * hv.w;
            }
        }
        if (eg == 0) {
            float al = __expf(zself - Em) * inv;
            float4 hv = h4[node * 16 + f];
            acc.x += al * hv.x;
            acc.y += al * hv.y;
            acc.z += al * hv.z;
            acc.w += al * hv.w;
        }
    }
#pragma unroll
    for (int o = 16; o <= 32; o <<= 1) {
        acc.x += __shfl_xor(acc.x, o);
        acc.y += __shfl_xor(acc.y, o);
        acc.z += __shfl_xor(acc.z, o);
        acc.w += __shfl_xor(acc.w, o);
    }
    if (eg == 0) {
        float4 bv = ((const float4*)bias)[f];
        float4 o4;
        o4.x = fmaxf(acc.x + bv.x, 0.f);
        o4.y = fmaxf(acc.y + bv.y, 0.f);
        o4.z = fmaxf(acc.z + bv.z, 0.f);
        o4.w = fmaxf(acc.w + bv.w, 0.f);
        ((float4*)out)[node * 16 + f] = o4;
    }
}

__global__ __launch_bounds__(256) void k_agg8(const float* __restrict__ h, const int* __restrict__ rowptr,
                                              const int* __restrict__ col, const float* __restrict__ as_,
                                              const float* __restrict__ ad_, const float* __restrict__ bias,
                                              float* __restrict__ out) {
    int node = blockIdx.x * 4 + (threadIdx.x >> 6);
    int lane = threadIdx.x & 63;
    if (node >= NN) return;
    int rp0 = rowptr[node];
    int deg = rowptr[node + 1] - rp0;
    float adn = ad_[node];
    float zself = lrelu(as_[node] + adn);
    const float2* h2v = (const float2*)h;
    int f = lane & 3, eg = lane >> 2;  // 16 edges x float2
    float2 acc = make_float2(0.f, 0.f);
    if (deg <= 64) {
        int s = 0;
        float z = -1e30f;
        if (lane < deg) {
            s = col[rp0 + lane];
            z = lrelu(as_[s] + adn);
        }
        float M = z;
#pragma unroll
        for (int o = 32; o; o >>= 1) M = fmaxf(M, __shfl_xor(M, o));
        M = fmaxf(M, zself);
        float ex = (lane < deg) ? __expf(z - M) : 0.f;
        float exs = __expf(zself - M);
        float sum = ex;
#pragma unroll
        for (int o = 32; o; o >>= 1) sum += __shfl_xor(sum, o);
        float inv = 1.f / (sum + exs);
        float wl = ex * inv;
        for (int base = 0; base < deg; base += 16) {
            int ia = base + eg;                 // <= 63 (deg<=64)
            int sa = __shfl(s, ia);
            float wa = __shfl(wl, ia);          // 0 beyond deg
            float2 hv = h2v[sa * 4 + f];
            acc.x += wa * hv.x;
            acc.y += wa * hv.y;
        }
        if (eg == 0) {
            float w0 = exs * inv;
            float2 hv = h2v[node * 4 + f];
            acc.x += w0 * hv.x;
            acc.y += w0 * hv.y;
        }
    } else {
        float m = -1e30f, l = 0.f;
        for (int i = lane; i < deg; i += 64) {
            float z = lrelu(as_[col[rp0 + i]] + adn);
            float mn = fmaxf(m, z);
            l = l * __expf(m - mn) + __expf(z - mn);
            m = mn;
        }
        if (lane == 0) {
            float mn = fmaxf(m, zself);
            l = l * __expf(m - mn) + __expf(zself - mn);
            m = mn;
        }
#pragma unroll
        for (int o = 32; o; o >>= 1) {
            float mo = __shfl_xor(m, o), lo = __shfl_xor(l, o);
            float mn = fmaxf(m, mo);
            l = l * __expf(m - mn) + lo * __expf(mo - mn);
            m = mn;
        }
        float Em = m;
        float inv = 1.f / l;
        for (int base = 0; base < deg; base += 16) {
            int i = base + eg;
            if (i < deg) {
                int sv = col[rp0 + i];
                float al = __expf(lrelu(as_[sv] + adn) - Em) * inv;
                float2 hv = h2v[sv * 4 + f];
                acc.x += al * hv.x;
                acc.y += al * hv.y;
            }
        }
        if (eg == 0) {
            float al = __expf(zself - Em) * inv;
            float2 hv = h2v[node * 4 + f];
            acc.x += al * hv.x;
            acc.y += al * hv.y;
        }
    }
#pragma unroll
    for (int o = 4; o <= 32; o <<= 1) {
        acc.x += __shfl_xor(acc.x, o);
        acc.y += __shfl_xor(acc.y, o);
    }
    if (eg == 0) {
        float2 bv = ((const float2*)bias)[f];
        float2 o2;
        o2.x = fmaxf(acc.x + bv.x, 0.f);
        o2.y = fmaxf(acc.y + bv.y, 0.f);
        ((float2*)out)[node * 4 + f] = o2;
    }
}

// ---------------- global mean pool + sigmoid ----------------

__global__ __launch_bounds__(256) void k_pool(const float* __restrict__ h3, const int* __restrict__ batch,
                                              float* __restrict__ pool, float* __restrict__ cntf) {
    __shared__ float pl[GG * CC + GG];
    for (int idx = threadIdx.x; idx < GG * CC + GG; idx += 256) pl[idx] = 0.f;
    __syncthreads();
    int node = blockIdx.x * 256 + threadIdx.x;
    if (node < NN) {
        int g = batch[node];
#pragma unroll
        for (int c = 0; c < CC; c++) atomicAdd(&pl[g * CC + c], h3[node * CC + c]);
        atomicAdd(&pl[GG * CC + g], 1.0f);
    }
    __syncthreads();
    for (int idx = threadIdx.x; idx < GG * CC + GG; idx += 256) {
        float v = pl[idx];
        if (idx < GG * CC)
            atomicAdd(&pool[idx], v);
        else
            atomicAdd(&cntf[idx - GG * CC], v);
    }
}

__global__ void k_final(const float* __restrict__ pool, const float* __restrict__ cntf,
                        float* __restrict__ out) {
    int t = threadIdx.x;
    if (t < GG * CC) {
        int g = t >> 3;
        float c = fmaxf(cntf[g], 1.0f);
        float v = pool[t] / c;
        out[t] = 1.0f / (1.0f + __expf(-v));
    }
}

// ---------------- launch ----------------

extern "C" void kernel_launch(void* const* d_in, const int* in_sizes, int n_in,
                              void* d_out, int out_size, void* d_ws, size_t ws_size,
                              hipStream_t stream) {
    const float* x   = (const float*)d_in[0];
    const int*   ei  = (const int*)d_in[1];
    const int*   bat = (const int*)d_in[3];
    const float* W1  = (const float*)d_in[4];
    const float* a1s = (const float*)d_in[5];
    const float* a1d = (const float*)d_in[6];
    const float* b1  = (const float*)d_in[7];
    const float* W2  = (const float*)d_in[8];
    const float* a2s = (const float*)d_in[9];
    const float* a2d = (const float*)d_in[10];
    const float* b2  = (const float*)d_in[11];
    const float* W3  = (const float*)d_in[12];
    const float* a3s = (const float*)d_in[13];
    const float* a3d = (const float*)d_in[14];
    const float* b3  = (const float*)d_in[15];
    float* out = (float*)d_out;

    float* hA  = (float*)d_ws;          // N*64 ; pairs aliases here (dead before mm writes)
    float* hB  = hA + NN * 64;          // N*64
    float* h3a = hB + NN * 64;          // N*8
    float* h3b = h3a + NN * 8;          // N*8
    float* as_ = h3b + NN * 8;          // N
    float* ad_ = as_ + NN;              // N
    int* rowptr  = (int*)(ad_ + NN);    // N+1
    int* col     = rowptr + NN + 1;     // E
    int* G       = col + EE;            // NCHK*NBKT
    int* offs    = G + NCHK * NBKT;     // NCHK*NBKT
    int* bT      = offs + NCHK * NBKT;  // NBKT
    int* bstart  = bT + NBKT;           // NBKT+1
    float* pool  = (float*)(bstart + NBKT + 1);
    float* cntf  = pool + GG * CC;
    uint2* pairs = (uint2*)hA;

    const int NB4  = (NN + 3) / 4;
    const int NB64 = (NN + 63) / 64;
    const int NBN  = (NN + 255) / 256;

    const int* srcE = ei;
    const int* dstE = ei + EE;

    kA1<<<NCHK, 256, 0, stream>>>(dstE, G);
    kA2<<<NBKT, 256, 0, stream>>>(G, offs, bT);
    kA2b<<<1, 256, 0, stream>>>(bT, bstart, pool, cntf, rowptr);
    kA3<<<NCHK, 256, 0, stream>>>(srcE, dstE, offs, bstart, pairs);
    kB<<<NBKT, 256, 0, stream>>>(pairs, bstart, col, rowptr);

    k_mm64t<11><<<NB64, 256, 0, stream>>>(x, W1, a1s, a1d, hA, as_, ad_);
    k_agg64<<<NB4, 256, 0, stream>>>(hA, rowptr, col, as_, ad_, b1, hB);
    k_mm64t<64><<<NB64, 256, 0, stream>>>(hB, W2, a2s, a2d, hA, as_, ad_);
    k_agg64<<<NB4, 256, 0, stream>>>(hA, rowptr, col, as_, ad_, b2, hB);
    k_mm8<<<NB4, 256, 0, stream>>>(hB, W3, a3s, a3d, h3a, as_, ad_);
    k_agg8<<<NB4, 256, 0, stream>>>(h3a, rowptr, col, as_, ad_, b3, h3b);
    k_pool<<<NBN, 256, 0, stream>>>(h3b, bat, pool, cntf);
    k_final<<<1, 512, 0, stream>>>(pool, cntf, out);
}

// Round 6
// 283.571 us; speedup vs baseline: 1.7630x; 1.0832x over previous
//
#include <hip/hip_runtime.h>
#include <hip/hip_bf16.h>

#define NN 50000
#define EE 800000
#define GG 64
#define CC 8

#define NBKT 196      // ceil(50000/256) buckets of 256 nodes
#define CHUNK 4096
#define NCHK 196      // ceil(800000/4096)
#define CAP 8192      // max edges per bucket (mean 4082)

__device__ __forceinline__ float lrelu(float z) { return fmaxf(z, 0.2f * z); }

__device__ __forceinline__ unsigned short f2bf(float v) {
    unsigned u = __float_as_uint(v);
    return (unsigned short)((u + 0x7FFFu + ((u >> 16) & 1u)) >> 16);  // RNE
}
__device__ __forceinline__ float bf2f(unsigned short b) {
    return __uint_as_float(((unsigned)b) << 16);
}

// ---------------- CSR build: two-level counting sort, 4B packed pairs ----------------

__global__ __launch_bounds__(256) void kA1(const int* __restrict__ dst, int* __restrict__ G) {
    __shared__ int hist[NBKT];
    int t = threadIdx.x;
    for (int i = t; i < NBKT; i += 256) hist[i] = 0;
    __syncthreads();
    int e0 = blockIdx.x * CHUNK;
    int e1 = min(e0 + CHUNK, EE);
    for (int e = e0 + t; e < e1; e += 256) atomicAdd(&hist[dst[e] >> 8], 1);
    __syncthreads();
    for (int i = t; i < NBKT; i += 256) G[blockIdx.x * NBKT + i] = hist[i];
}

__global__ __launch_bounds__(256) void kA2(const int* __restrict__ G, int* __restrict__ offs,
                                           int* __restrict__ bT) {
    __shared__ int s[256];
    int t = threadIdx.x, j = blockIdx.x;
    int v = (t < NCHK) ? G[t * NBKT + j] : 0;
    s[t] = v;
    __syncthreads();
#pragma unroll
    for (int off = 1; off < 256; off <<= 1) {
        int u = (t >= off) ? s[t - off] : 0;
        __syncthreads();
        s[t] += u;
        __syncthreads();
    }
    if (t < NCHK) offs[t * NBKT + j] = s[t] - v;
    if (t == 255) bT[j] = s[255];
}

__global__ __launch_bounds__(256) void kA2b(const int* __restrict__ bT, int* __restrict__ bstart,
                                            float* __restrict__ pool, float* __restrict__ cntf,
                                            int* __restrict__ rowptr) {
    __shared__ int s[256];
    int t = threadIdx.x;
    int v = (t < NBKT) ? bT[t] : 0;
    s[t] = v;
    __syncthreads();
#pragma unroll
    for (int off = 1; off < 256; off <<= 1) {
        int u = (t >= off) ? s[t - off] : 0;
        __syncthreads();
        s[t] += u;
        __syncthreads();
    }
    if (t < NBKT) bstart[t] = s[t] - v;
    if (t == 0) { bstart[NBKT] = EE; rowptr[NN] = EE; }
    for (int i = t; i < GG * CC; i += 256) pool[i] = 0.f;
    if (t < GG) cntf[t] = 0.f;
}

__global__ __launch_bounds__(256) void kA3(const int* __restrict__ src, const int* __restrict__ dst,
                                           const int* __restrict__ offs, const int* __restrict__ bstart,
                                           unsigned* __restrict__ pairs) {
    __shared__ int cur[NBKT];
    int t = threadIdx.x, c = blockIdx.x;
    for (int i = t; i < NBKT; i += 256) cur[i] = bstart[i] + offs[c * NBKT + i];
    __syncthreads();
    int e0 = c * CHUNK, e1 = min(e0 + CHUNK, EE);
    for (int e = e0 + t; e < e1; e += 256) {
        int d = dst[e];
        int pos = atomicAdd(&cur[d >> 8], 1);
        pairs[pos] = (unsigned)src[e] | ((unsigned)(d & 255) << 16);  // src<2^16, dlocal<2^8
    }
}

__global__ __launch_bounds__(256) void kB(const unsigned* __restrict__ pairs, const int* __restrict__ bstart,
                                          int* __restrict__ col, int* __restrict__ rowptr) {
    __shared__ unsigned pL[CAP];
    __shared__ int hist[256];
    __shared__ int sc[256];
    int t = threadIdx.x, j = blockIdx.x;
    int start = bstart[j], end = bstart[j + 1];
    int cnt = end - start;
    if (cnt > CAP) cnt = CAP;
    int nb = j * 256;
    int nodeCnt = min(256, NN - nb);
    hist[t] = 0;
    __syncthreads();
    for (int i = t; i < cnt; i += 256) {
        unsigned p = pairs[start + i];
        pL[i] = p;
        atomicAdd(&hist[p >> 16], 1);
    }
    __syncthreads();
    int c = hist[t];
    sc[t] = c;
    __syncthreads();
#pragma unroll
    for (int off = 1; off < 256; off <<= 1) {
        int u = (t >= off) ? sc[t - off] : 0;
        __syncthreads();
        sc[t] += u;
        __syncthreads();
    }
    int excl = sc[t] - c;
    if (t < nodeCnt) rowptr[nb + t] = start + excl;
    hist[t] = excl;
    __syncthreads();
    for (int i = t; i < cnt; i += 256) {
        unsigned p = pL[i];
        int pos = atomicAdd(&hist[p >> 16], 1);
        col[start + pos] = (int)(p & 0xFFFFu);
    }
}

// ---------------- tiled h = x @ W (out=64, stored bf16) + fp32 alpha scalars ----------------

template <int IN>
__global__ __launch_bounds__(256) void k_mm64t(const float* __restrict__ x, const float* __restrict__ W,
                                               const float* __restrict__ avs, const float* __restrict__ avd,
                                               unsigned short* __restrict__ h, float* __restrict__ as_,
                                               float* __restrict__ ad_) {
    __shared__ float xT[IN * 68];
    __shared__ float Wl[IN * 64];
    __shared__ float avl[64], adl[64];
    int t = threadIdx.x;
    int nbase = blockIdx.x * 64;
    for (int idx = t; idx < IN * 64; idx += 256) Wl[idx] = W[idx];
    if (t < 64) { avl[t] = avs[t]; adl[t] = avd[t]; }
    for (int idx = t; idx < 64 * IN; idx += 256) {
        int n = idx / IN, k = idx - n * IN;
        int gn = nbase + n;
        if (gn >= NN) gn = NN - 1;
        xT[k * 68 + n] = x[gn * IN + k];
    }
    __syncthreads();
    int f0 = (t & 15) * 4;
    int n0 = (t >> 4) * 4;
    float a00=0,a01=0,a02=0,a03=0, a10=0,a11=0,a12=0,a13=0;
    float a20=0,a21=0,a22=0,a23=0, a30=0,a31=0,a32=0,a33=0;
#pragma unroll 4
    for (int k = 0; k < IN; k++) {
        float4 xv = *(const float4*)&xT[k * 68 + n0];
        float4 wv = *(const float4*)&Wl[k * 64 + f0];
        a00 += xv.x * wv.x; a01 += xv.x * wv.y; a02 += xv.x * wv.z; a03 += xv.x * wv.w;
        a10 += xv.y * wv.x; a11 += xv.y * wv.y; a12 += xv.y * wv.z; a13 += xv.y * wv.w;
        a20 += xv.z * wv.x; a21 += xv.z * wv.y; a22 += xv.z * wv.z; a23 += xv.z * wv.w;
        a30 += xv.w * wv.x; a31 += xv.w * wv.y; a32 += xv.w * wv.z; a33 += xv.w * wv.w;
    }
    float4 av = *(const float4*)&avl[f0];
    float4 dv = *(const float4*)&adl[f0];
    float vs[4], vd[4];
    vs[0] = a00*av.x + a01*av.y + a02*av.z + a03*av.w;
    vs[1] = a10*av.x + a11*av.y + a12*av.z + a13*av.w;
    vs[2] = a20*av.x + a21*av.y + a22*av.z + a23*av.w;
    vs[3] = a30*av.x + a31*av.y + a32*av.z + a33*av.w;
    vd[0] = a00*dv.x + a01*dv.y + a02*dv.z + a03*dv.w;
    vd[1] = a10*dv.x + a11*dv.y + a12*dv.z + a13*dv.w;
    vd[2] = a20*dv.x + a21*dv.y + a22*dv.z + a23*dv.w;
    vd[3] = a30*dv.x + a31*dv.y + a32*dv.z + a33*dv.w;
#pragma unroll
    for (int o = 1; o < 16; o <<= 1) {
#pragma unroll
        for (int ni = 0; ni < 4; ni++) {
            vs[ni] += __shfl_xor(vs[ni], o);
            vd[ni] += __shfl_xor(vd[ni], o);
        }
    }
    ushort4* h4 = (ushort4*)h;  // row = 16 x ushort4
    int nn0 = nbase + n0;
    float rows[4][4] = {{a00,a01,a02,a03},{a10,a11,a12,a13},{a20,a21,a22,a23},{a30,a31,a32,a33}};
#pragma unroll
    for (int ni = 0; ni < 4; ni++) {
        if (nn0 + ni < NN) {
            ushort4 pv;
            pv.x = f2bf(rows[ni][0]); pv.y = f2bf(rows[ni][1]);
            pv.z = f2bf(rows[ni][2]); pv.w = f2bf(rows[ni][3]);
            h4[(nn0 + ni) * 16 + (t & 15)] = pv;
            if ((t & 15) == 0) { as_[nn0 + ni] = vs[ni]; ad_[nn0 + ni] = vd[ni]; }
        }
    }
}

// layer 3: h3 = x @ W3 (64x8, stored bf16) + alpha scalars; wave per node
__global__ __launch_bounds__(256) void k_mm8(const float* __restrict__ x, const float* __restrict__ W,
                                             const float* __restrict__ avs, const float* __restrict__ avd,
                                             unsigned short* __restrict__ h3, float* __restrict__ as_,
                                             float* __restrict__ ad_) {
    __shared__ float Wl[512];
    for (int idx = threadIdx.x; idx < 512; idx += 256) Wl[idx] = W[idx];
    __syncthreads();
    int node = blockIdx.x * 4 + (threadIdx.x >> 6);
    int lane = threadIdx.x & 63;
    if (node >= NN) return;
    int f = lane & 7, kc = lane >> 3;
    float xv = x[node * 64 + lane];
    float acc = 0.f;
#pragma unroll
    for (int j = 0; j < 8; j++) {
        int k = kc * 8 + j;
        acc += __shfl(xv, k) * Wl[k * 8 + f];
    }
    acc += __shfl_xor(acc, 8);
    acc += __shfl_xor(acc, 16);
    acc += __shfl_xor(acc, 32);
    if (lane < 8) h3[node * 8 + lane] = f2bf(acc);
    float vs = 0.f, vd = 0.f;
    if (lane < 8) {
        vs = acc * avs[lane];
        vd = acc * avd[lane];
    }
    vs += __shfl_xor(vs, 1); vs += __shfl_xor(vs, 2); vs += __shfl_xor(vs, 4);
    vd += __shfl_xor(vd, 1); vd += __shfl_xor(vd, 2); vd += __shfl_xor(vd, 4);
    if (lane == 0) {
        as_[node] = vs;
        ad_[node] = vd;
    }
}

// ---------------- GAT aggregation ----------------
// Fast path: lane i owns edge i; (w,s) staged once in LDS; phase C reads
// 2 edges per ds_read_b128, gathers bf16 rows (8B/lane), w=0 padding (no tail).

__global__ __launch_bounds__(256) void k_agg64(const unsigned short* __restrict__ h,
                                               const int* __restrict__ rowptr,
                                               const int* __restrict__ col, const float* __restrict__ as_,
                                               const float* __restrict__ ad_, const float* __restrict__ bias,
                                               float* __restrict__ out) {
    __shared__ uint2 ws[4][64];
    int wid = threadIdx.x >> 6;
    int node = blockIdx.x * 4 + wid;   // NN = 12500*4: every wave valid
    int lane = threadIdx.x & 63;
    int rp0 = rowptr[node];
    int deg = rowptr[node + 1] - rp0;
    float adn = ad_[node];
    float zself = lrelu(as_[node] + adn);
    const ushort4* hb = (const ushort4*)h;
    int f = lane & 15, eg = lane >> 4;
    float4 acc = make_float4(0.f, 0.f, 0.f, 0.f);
    if (deg <= 64) {
        int s = 0;
        float z = -1e30f;
        if (lane < deg) {
            s = col[rp0 + lane];
            z = lrelu(as_[s] + adn);
        }
        float M = z;
#pragma unroll
        for (int o = 32; o; o >>= 1) M = fmaxf(M, __shfl_xor(M, o));
        M = fmaxf(M, zself);
        float ex = (lane < deg) ? __expf(z - M) : 0.f;
        float exs = __expf(zself - M);
        float sum = ex;
#pragma unroll
        for (int o = 32; o; o >>= 1) sum += __shfl_xor(sum, o);
        float inv = 1.f / (sum + exs);
        float wl = ex * inv;   // 0 beyond deg
        ws[wid][lane] = make_uint2(__float_as_uint(wl), (unsigned)s);
        __syncthreads();       // one barrier per wave (both paths)
        const uint4* wsp = (const uint4*)&ws[wid][0];
        for (int base = 0; base < deg; base += 8) {
            uint4 p = wsp[(base >> 1) + eg];
            float wa = __uint_as_float(p.x);
            float wb = __uint_as_float(p.z);
            ushort4 ha = hb[p.y * 16 + f];
            ushort4 hc = hb[p.w * 16 + f];
            acc.x += wa * bf2f(ha.x) + wb * bf2f(hc.x);
            acc.y += wa * bf2f(ha.y) + wb * bf2f(hc.y);
            acc.z += wa * bf2f(ha.z) + wb * bf2f(hc.z);
            acc.w += wa * bf2f(ha.w) + wb * bf2f(hc.w);
        }
        if (eg == 0) {
            float w0 = exs * inv;
            ushort4 hv = hb[node * 16 + f];
            acc.x += w0 * bf2f(hv.x);
            acc.y += w0 * bf2f(hv.y);
            acc.z += w0 * bf2f(hv.z);
            acc.w += w0 * bf2f(hv.w);
        }
    } else {
        __syncthreads();       // match barrier count
        float m = -1e30f, l = 0.f;
        for (int i = lane; i < deg; i += 64) {
            float z = lrelu(as_[col[rp0 + i]] + adn);
            float mn = fmaxf(m, z);
            l = l * __expf(m - mn) + __expf(z - mn);
            m = mn;
        }
        if (lane == 0) {
            float mn = fmaxf(m, zself);
            l = l * __expf(m - mn) + __expf(zself - mn);
            m = mn;
        }
#pragma unroll
        for (int o = 32; o; o >>= 1) {
            float mo = __shfl_xor(m, o), lo = __shfl_xor(l, o);
            float mn = fmaxf(m, mo);
            l = l * __expf(m - mn) + lo * __expf(mo - mn);
            m = mn;
        }
        float Em = m;
        float inv = 1.f / l;
        for (int base = 0; base < deg; base += 4) {
            int i = base + eg;
            if (i < deg) {
                int sv = col[rp0 + i];
                float al = __expf(lrelu(as_[sv] + adn) - Em) * inv;
                ushort4 hv = hb[sv * 16 + f];
                acc.x += al * bf2f(hv.x);
                acc.y += al * bf2f(hv.y);
                acc.z += al * bf2f(hv.z);
                acc.w += al * bf2f(hv.w);
            }
        }
        if (eg == 0) {
            float al = __expf(zself - Em) * inv;
            ushort4 hv = hb[node * 16 + f];
            acc.x += al * bf2f(hv.x);
            acc.y += al * bf2f(hv.y);
            acc.z += al * bf2f(hv.z);
            acc.w += al * bf2f(hv.w);
        }
    }
#pragma unroll
    for (int o = 16; o <= 32; o <<= 1) {
        acc.x += __shfl_xor(acc.x, o);
        acc.y += __shfl_xor(acc.y, o);
        acc.z += __shfl_xor(acc.z, o);
        acc.w += __shfl_xor(acc.w, o);
    }
    if (eg == 0) {
        float4 bv = ((const float4*)bias)[f];
        float4 o4;
        o4.x = fmaxf(acc.x + bv.x, 0.f);
        o4.y = fmaxf(acc.y + bv.y, 0.f);
        o4.z = fmaxf(acc.z + bv.z, 0.f);
        o4.w = fmaxf(acc.w + bv.w, 0.f);
        ((float4*)out)[node * 16 + f] = o4;
    }
}

// layer-3 aggregation: bf16 rows of 8; 16 groups x 2 edges per ds_read_b128
__global__ __launch_bounds__(256) void k_agg8(const unsigned short* __restrict__ h,
                                              const int* __restrict__ rowptr,
                                              const int* __restrict__ col, const float* __restrict__ as_,
                                              const float* __restrict__ ad_, const float* __restrict__ bias,
                                              float* __restrict__ out) {
    __shared__ uint2 ws[4][64];
    int wid = threadIdx.x >> 6;
    int node = blockIdx.x * 4 + wid;
    int lane = threadIdx.x & 63;
    int rp0 = rowptr[node];
    int deg = rowptr[node + 1] - rp0;
    float adn = ad_[node];
    float zself = lrelu(as_[node] + adn);
    const ushort2* h2v = (const ushort2*)h;  // row = 4 x ushort2
    int f = lane & 3, eg = lane >> 2;        // 16 groups of 4 lanes
    float2 acc = make_float2(0.f, 0.f);
    if (deg <= 64) {
        int s = 0;
        float z = -1e30f;
        if (lane < deg) {
            s = col[rp0 + lane];
            z = lrelu(as_[s] + adn);
        }
        float M = z;
#pragma unroll
        for (int o = 32; o; o >>= 1) M = fmaxf(M, __shfl_xor(M, o));
        M = fmaxf(M, zself);
        float ex = (lane < deg) ? __expf(z - M) : 0.f;
        float exs = __expf(zself - M);
        float sum = ex;
#pragma unroll
        for (int o = 32; o; o >>= 1) sum += __shfl_xor(sum, o);
        float inv = 1.f / (sum + exs);
        float wl = ex * inv;
        ws[wid][lane] = make_uint2(__float_as_uint(wl), (unsigned)s);
        __syncthreads();
        const uint4* wsp = (const uint4*)&ws[wid][0];
        for (int base = 0; base < deg; base += 32) {   // 16 groups x 2 edges
            uint4 p = wsp[(base >> 1) + eg];
            float wa = __uint_as_float(p.x);
            float wb = __uint_as_float(p.z);
            ushort2 ha = h2v[p.y * 4 + f];
            ushort2 hc = h2v[p.w * 4 + f];
            acc.x += wa * bf2f(ha.x) + wb * bf2f(hc.x);
            acc.y += wa * bf2f(ha.y) + wb * bf2f(hc.y);
        }
        if (eg == 0) {
            float w0 = exs * inv;
            ushort2 hv = h2v[node * 4 + f];
            acc.x += w0 * bf2f(hv.x);
            acc.y += w0 * bf2f(hv.y);
        }
    } else {
        __syncthreads();
        float m = -1e30f, l = 0.f;
        for (int i = lane; i < deg; i += 64) {
            float z = lrelu(as_[col[rp0 + i]] + adn);
            float mn = fmaxf(m, z);
            l = l * __expf(m - mn) + __expf(z - mn);
            m = mn;
        }
        if (lane == 0) {
            float mn = fmaxf(m, zself);
            l = l * __expf(m - mn) + __expf(zself - mn);
            m = mn;
        }
#pragma unroll
        for (int o = 32; o; o >>= 1) {
            float mo = __shfl_xor(m, o), lo = __shfl_xor(l, o);
            float mn = fmaxf(m, mo);
            l = l * __expf(m - mn) + lo * __expf(mo - mn);
            m = mn;
        }
        float Em = m;
        float inv = 1.f / l;
        for (int base = 0; base < deg; base += 16) {
            int i = base + eg;
            if (i < deg) {
                int sv = col[rp0 + i];
                float al = __expf(lrelu(as_[sv] + adn) - Em) * inv;
                ushort2 hv = h2v[sv * 4 + f];
                acc.x += al * bf2f(hv.x);
                acc.y += al * bf2f(hv.y);
            }
        }
        if (eg == 0) {
            float al = __expf(zself - Em) * inv;
            ushort2 hv = h2v[node * 4 + f];
            acc.x += al * bf2f(hv.x);
            acc.y += al * bf2f(hv.y);
        }
    }
#pragma unroll
    for (int o = 4; o <= 32; o <<= 1) {
        acc.x += __shfl_xor(acc.x, o);
        acc.y += __shfl_xor(acc.y, o);
    }
    if (eg == 0) {
        float2 bv = ((const float2*)bias)[f];
        float2 o2;
        o2.x = fmaxf(acc.x + bv.x, 0.f);
        o2.y = fmaxf(acc.y + bv.y, 0.f);
        ((float2*)out)[node * 4 + f] = o2;
    }
}

// ---------------- global mean pool + sigmoid ----------------

__global__ __launch_bounds__(256) void k_pool(const float* __restrict__ h3, const int* __restrict__ batch,
                                              float* __restrict__ pool, float* __restrict__ cntf) {
    __shared__ float pl[GG * CC + GG];
    for (int idx = threadIdx.x; idx < GG * CC + GG; idx += 256) pl[idx] = 0.f;
    __syncthreads();
    int node = blockIdx.x * 256 + threadIdx.x;
    if (node < NN) {
        int g = batch[node];
#pragma unroll
        for (int c = 0; c < CC; c++) atomicAdd(&pl[g * CC + c], h3[node * CC + c]);
        atomicAdd(&pl[GG * CC + g], 1.0f);
    }
    __syncthreads();
    for (int idx = threadIdx.x; idx < GG * CC + GG; idx += 256) {
        float v = pl[idx];
        if (idx < GG * CC)
            atomicAdd(&pool[idx], v);
        else
            atomicAdd(&cntf[idx - GG * CC], v);
    }
}

__global__ void k_final(const float* __restrict__ pool, const float* __restrict__ cntf,
                        float* __restrict__ out) {
    int t = threadIdx.x;
    if (t < GG * CC) {
        int g = t >> 3;
        float c = fmaxf(cntf[g], 1.0f);
        float v = pool[t] / c;
        out[t] = 1.0f / (1.0f + __expf(-v));
    }
}

// ---------------- launch ----------------

extern "C" void kernel_launch(void* const* d_in, const int* in_sizes, int n_in,
                              void* d_out, int out_size, void* d_ws, size_t ws_size,
                              hipStream_t stream) {
    const float* x   = (const float*)d_in[0];
    const int*   ei  = (const int*)d_in[1];
    const int*   bat = (const int*)d_in[3];
    const float* W1  = (const float*)d_in[4];
    const float* a1s = (const float*)d_in[5];
    const float* a1d = (const float*)d_in[6];
    const float* b1  = (const float*)d_in[7];
    const float* W2  = (const float*)d_in[8];
    const float* a2s = (const float*)d_in[9];
    const float* a2d = (const float*)d_in[10];
    const float* b2  = (const float*)d_in[11];
    const float* W3  = (const float*)d_in[12];
    const float* a3s = (const float*)d_in[13];
    const float* a3d = (const float*)d_in[14];
    const float* b3  = (const float*)d_in[15];
    float* out = (float*)d_out;

    float* hA  = (float*)d_ws;          // N*64 floats; used as bf16 h (first half) / pairs alias
    float* hB  = hA + NN * 64;          // N*64 fp32 (agg outputs)
    float* h3a = hB + NN * 64;          // N*8 (bf16 use)
    float* h3b = h3a + NN * 8;          // N*8 fp32
    float* as_ = h3b + NN * 8;          // N
    float* ad_ = as_ + NN;              // N
    int* rowptr  = (int*)(ad_ + NN);    // N+1
    int* col     = rowptr + NN + 1;     // E
    int* G       = col + EE;            // NCHK*NBKT
    int* offs    = G + NCHK * NBKT;     // NCHK*NBKT
    int* bT      = offs + NCHK * NBKT;  // NBKT
    int* bstart  = bT + NBKT;           // NBKT+1
    float* pool  = (float*)(bstart + NBKT + 1);
    float* cntf  = pool + GG * CC;
    unsigned* pairs = (unsigned*)hA;    // E x 4B (3.2MB), dead before mm writes hA

    unsigned short* hA16 = (unsigned short*)hA;
    unsigned short* h316 = (unsigned short*)h3a;

    const int NB4  = (NN + 3) / 4;
    const int NB64 = (NN + 63) / 64;
    const int NBN  = (NN + 255) / 256;

    const int* srcE = ei;
    const int* dstE = ei + EE;

    kA1<<<NCHK, 256, 0, stream>>>(dstE, G);
    kA2<<<NBKT, 256, 0, stream>>>(G, offs, bT);
    kA2b<<<1, 256, 0, stream>>>(bT, bstart, pool, cntf, rowptr);
    kA3<<<NCHK, 256, 0, stream>>>(srcE, dstE, offs, bstart, pairs);
    kB<<<NBKT, 256, 0, stream>>>(pairs, bstart, col, rowptr);

    k_mm64t<11><<<NB64, 256, 0, stream>>>(x, W1, a1s, a1d, hA16, as_, ad_);
    k_agg64<<<NB4, 256, 0, stream>>>(hA16, rowptr, col, as_, ad_, b1, hB);
    k_mm64t<64><<<NB64, 256, 0, stream>>>(hB, W2, a2s, a2d, hA16, as_, ad_);
    k_agg64<<<NB4, 256, 0, stream>>>(hA16, rowptr, col, as_, ad_, b2, hB);
    k_mm8<<<NB4, 256, 0, stream>>>(hB, W3, a3s, a3d, h316, as_, ad_);
    k_agg8<<<NB4, 256, 0, stream>>>(h316, rowptr, col, as_, ad_, b3, h3b);
    k_pool<<<NBN, 256, 0, stream>>>(h3b, bat, pool, cntf);
    k_final<<<1, 512, 0, stream>>>(pool, cntf, out);
}